// Round 12
// baseline (795.119 us; speedup 1.0000x reference)
//
#include <hip/hip_runtime.h>
#include <hip/hip_fp16.h>

#define N_NODES 50000
#define N_EDGES 800000
#define B_GRAPH 256
#define IN_DIM  128
#define HID     64
#define NBLK_SCAN ((N_NODES + 1023) / 1024)   // 49

typedef _Float16 f16x8 __attribute__((ext_vector_type(8)));
typedef float    f32x4 __attribute__((ext_vector_type(4)));

// ---------- fused setup: histogram + z-latent + weight transposes + stats zero ----------
__global__ __launch_bounds__(256) void k_setup(const int* __restrict__ dst,
                                               int* __restrict__ counts,
                                               const float* __restrict__ z,
                                               const float* __restrict__ lw,
                                               const float* __restrict__ lb,
                                               float* __restrict__ p,
                                               const float* __restrict__ w1a,
                                               const float* __restrict__ w2a,
                                               const float* __restrict__ w1b,
                                               const float* __restrict__ w2b,
                                               const float* __restrict__ w1c,
                                               const float* __restrict__ w2c,
                                               _Float16* __restrict__ wtbuf,
                                               float* __restrict__ stats) {
    int idx = blockIdx.x * blockDim.x + threadIdx.x;   // grid covers N_EDGES
    if (idx < N_EDGES) atomicAdd(&counts[dst[idx]], 1);
    if (idx < 3 * 512) stats[idx] = 0.f;
    if (idx < 3 * 16384) {                              // weight transpose, 3 layers
        int l = idx >> 14, r = idx & 16383;
        const float* w1 = (l == 0) ? w1a : ((l == 1) ? w1b : w1c);
        const float* w2 = (l == 0) ? w2a : ((l == 1) ? w2b : w2c);
        _Float16* o = wtbuf + l * 16384;
        if (r < 8192) { int k = r >> 7, c = r & 127; o[c * 64 + k] = (_Float16)w1[r]; }
        else { int q = r - 8192; int k = q >> 6, c = q & 63; o[8192 + c * 128 + k] = (_Float16)w2[q]; }
    }
    if (idx < B_GRAPH * HID) {                          // p = relu(z @ lin_w + lin_b)
        int row = idx >> 6, c = idx & 63;
        float acc = lb[c];
        const float* zr = z + row * IN_DIM;
#pragma unroll 8
        for (int k = 0; k < IN_DIM; ++k) acc = fmaf(zr[k], lw[k * HID + c], acc);
        p[idx] = fmaxf(acc, 0.f);
    }
}

// -------------------- CSR scan (two-level) --------------------
__global__ __launch_bounds__(1024) void k_scanA(const int* __restrict__ counts,
                                                int* __restrict__ rowstart,
                                                int* __restrict__ btot) {
    __shared__ int wsum[16];
    int tid = threadIdx.x, lane = tid & 63, w = tid >> 6;
    int i = blockIdx.x * 1024 + tid;
    int v = (i < N_NODES) ? counts[i] : 0;
    int s = v;
#pragma unroll
    for (int off = 1; off < 64; off <<= 1) {
        int t = __shfl_up(s, off, 64);
        if (lane >= off) s += t;
    }
    if (lane == 63) wsum[w] = s;
    __syncthreads();
    if (w == 0) {
        int ws = (lane < 16) ? wsum[lane] : 0;
#pragma unroll
        for (int off = 1; off < 16; off <<= 1) {
            int t = __shfl_up(ws, off, 64);
            if (lane >= off) ws += t;
        }
        if (lane < 16) wsum[lane] = ws;
    }
    __syncthreads();
    int wbase = (w == 0) ? 0 : wsum[w - 1];
    if (i < N_NODES) rowstart[i] = wbase + s - v;
    if (tid == 0) btot[blockIdx.x] = wsum[15];
}

__global__ __launch_bounds__(64) void k_scanB(const int* __restrict__ btot,
                                              int* __restrict__ boff) {
    int lane = threadIdx.x;
    int v = (lane < NBLK_SCAN) ? btot[lane] : 0;
    int s = v;
#pragma unroll
    for (int off = 1; off < 64; off <<= 1) {
        int t = __shfl_up(s, off, 64);
        if (lane >= off) s += t;
    }
    if (lane < NBLK_SCAN) boff[lane] = s - v;
    if (lane == 63) boff[NBLK_SCAN] = s;
}

__global__ __launch_bounds__(256) void k_scanC(int* __restrict__ rowstart,
                                               const int* __restrict__ boff,
                                               int* __restrict__ cursor) {
    int i = blockIdx.x * blockDim.x + threadIdx.x;
    if (i < N_NODES) {
        int r = rowstart[i] + boff[i >> 10];
        rowstart[i] = r;
        cursor[i] = r;
    } else if (i == N_NODES) {
        rowstart[N_NODES] = boff[NBLK_SCAN];
    }
}

// ---------- fused: CSR scatter + packed fp16 attr (R8-proven) + latent gather ----------
__global__ __launch_bounds__(256) void k_scatgath(const int* __restrict__ src,
                                                  const int* __restrict__ dst,
                                                  const float* __restrict__ ea,
                                                  int* __restrict__ cursor,
                                                  int* __restrict__ csr_src,
                                                  __half2* __restrict__ attr_h,
                                                  const float* __restrict__ p,
                                                  const int* __restrict__ batch,
                                                  _Float16* __restrict__ x0h) {
    int idx = blockIdx.x * blockDim.x + threadIdx.x;
    if (idx < N_EDGES) {
        int d = dst[idx];
        int pos = atomicAdd(&cursor[d], 1);
        csr_src[pos] = src[idx];
        const float4* s0 = (const float4*)(ea + (size_t)idx * 16);
        float4 f0 = s0[0], f1 = s0[1], f2 = s0[2], f3 = s0[3];
        uint4 u0, u1;
        u0.x = __builtin_bit_cast(unsigned, __floats2half2_rn(f0.x, f0.y));
        u0.y = __builtin_bit_cast(unsigned, __floats2half2_rn(f0.z, f0.w));
        u0.z = __builtin_bit_cast(unsigned, __floats2half2_rn(f1.x, f1.y));
        u0.w = __builtin_bit_cast(unsigned, __floats2half2_rn(f1.z, f1.w));
        u1.x = __builtin_bit_cast(unsigned, __floats2half2_rn(f2.x, f2.y));
        u1.y = __builtin_bit_cast(unsigned, __floats2half2_rn(f2.z, f2.w));
        u1.z = __builtin_bit_cast(unsigned, __floats2half2_rn(f3.x, f3.y));
        u1.w = __builtin_bit_cast(unsigned, __floats2half2_rn(f3.z, f3.w));
        uint4* op = (uint4*)(attr_h + (size_t)pos * 8);
        op[0] = u0;
        op[1] = u1;
    }
    if (idx < N_NODES * 16) {                           // x0h[n] = fp16(p[batch[n]])
        int n = idx >> 4, q = idx & 15;
        float4 v = ((const float4*)(p + batch[n] * 64))[q];
        uint2 u;
        u.x = __builtin_bit_cast(unsigned, __floats2half2_rn(v.x, v.y));
        u.y = __builtin_bit_cast(unsigned, __floats2half2_rn(v.z, v.w));
        ((uint2*)(x0h + (size_t)n * 64 + q * 4))[0] = u;
    }
}

// -------------------- edge pass: one wave per node, 8-edge chunks (R8/R11-proven) -------
__global__ __launch_bounds__(256) void k_edge(const _Float16* __restrict__ y,
                                              const float* __restrict__ s2,
                                              const float* __restrict__ bg,
                                              const float* __restrict__ bb,
                                              float relu_neg,
                                              const int* __restrict__ rowstart,
                                              const int* __restrict__ csr_src,
                                              const _Float16* __restrict__ attr_h,
                                              const float* __restrict__ ew,
                                              const float* __restrict__ eb,
                                              _Float16* __restrict__ agg16) {
    int tid = threadIdx.x, lane = tid & 63;
    __half2 rw2[8];
#pragma unroll
    for (int k = 0; k < 8; ++k)
        rw2[k] = __floats2half2_rn(ew[(2 * k) * 64 + lane], ew[(2 * k + 1) * 64 + lane]);
    float ebl = eb[lane];
    float sA = 1.f, sB = 0.f;
    if (s2) {
        float mu  = s2[lane] * (1.f / N_NODES);
        float var = s2[64 + lane] * (1.f / N_NODES) - mu * mu;
        sA = rsqrtf(var + 1e-5f) * bg[lane];
        sB = bb[lane] - mu * sA;
    }
    const __half2 hz = __float2half2_rn(0.f);
    int wave = blockIdx.x * 4 + (tid >> 6);
    int nw = gridDim.x * 4;
    for (int n0 = wave; n0 < N_NODES; n0 += nw) {
        int n = __builtin_amdgcn_readfirstlane(n0);
        int beg = rowstart[n], end = rowstart[n + 1];
        float xr = fmaxf(fmaf((float)y[(size_t)n * 64 + lane], sA, sB), relu_neg);
        float num = 0.f, den = 0.f;
        for (int i = beg; i < end; i += 8) {
            int lim = end - 1;
            int sv = csr_src[min(i + (lane & 7), lim)];
            float xs[8];
            uint4 ua[8], ub[8];
#pragma unroll
            for (int j = 0; j < 8; ++j) {
                int s = __builtin_amdgcn_readlane(sv, j);
                xs[j] = (float)y[(size_t)s * 64 + lane];
                int ej = min(i + j, lim);               // wave-uniform
                const uint4* ap = (const uint4*)(attr_h + (size_t)ej * 16);
                ua[j] = ap[0];
                ub[j] = ap[1];
            }
            int ns = end - i;
#pragma unroll
            for (int j = 0; j < 8; ++j) {
                if (j < ns) {
                    __half2 aE = hz, aO = hz;
                    aE = __hfma2(__builtin_bit_cast(__half2, ua[j].x), rw2[0], aE);
                    aO = __hfma2(__builtin_bit_cast(__half2, ua[j].y), rw2[1], aO);
                    aE = __hfma2(__builtin_bit_cast(__half2, ua[j].z), rw2[2], aE);
                    aO = __hfma2(__builtin_bit_cast(__half2, ua[j].w), rw2[3], aO);
                    aE = __hfma2(__builtin_bit_cast(__half2, ub[j].x), rw2[4], aE);
                    aO = __hfma2(__builtin_bit_cast(__half2, ub[j].y), rw2[5], aO);
                    aE = __hfma2(__builtin_bit_cast(__half2, ub[j].z), rw2[6], aE);
                    aO = __hfma2(__builtin_bit_cast(__half2, ub[j].w), rw2[7], aO);
                    float el = ebl + (__low2float(aE) + __high2float(aE))
                                   + (__low2float(aO) + __high2float(aO));
                    float xv = fmaxf(fmaf(xs[j], sA, sB), relu_neg);
                    float m  = fmaxf(xv + el, 0.f) + 1e-7f;
                    float e2 = __expf(m);
                    num = fmaf(m, e2, num);
                    den += e2;
                }
            }
        }
        agg16[(size_t)n * 64 + lane] = (_Float16)(num / (den + 1e-16f) + xr);
    }
}

// -------------------- MFMA mlp1: t16[N,128] = agg16[N,64] @ w1 + b1 ; stats ------------
__global__ __launch_bounds__(256) void k_mlp1(const _Float16* __restrict__ agg16,
                                              const _Float16* __restrict__ w1t,
                                              const float* __restrict__ b1,
                                              _Float16* __restrict__ t16,
                                              float* __restrict__ s1) {
    int tid = threadIdx.x, l = tid & 63;
    int cl = l & 15, kg = l >> 4;
#define DB1(n) \
    f16x8 b##n##_0 = *(const f16x8*)&w1t[((n) * 16 + cl) * 64 + kg * 8]; \
    f16x8 b##n##_1 = *(const f16x8*)&w1t[((n) * 16 + cl) * 64 + 32 + kg * 8]; \
    float bias##n = b1[(n) * 16 + cl]; float sum##n = 0.f, sq##n = 0.f;
    DB1(0) DB1(1) DB1(2) DB1(3) DB1(4) DB1(5) DB1(6) DB1(7)
#undef DB1
    int wid = blockIdx.x * 4 + (tid >> 6);
    for (int t = wid; t < N_NODES / 16; t += gridDim.x * 4) {
        int m0 = t * 16;
        const uint4* ap = (const uint4*)(agg16 + (size_t)(m0 + cl) * 64 + kg * 8);
        f16x8 a0 = __builtin_bit_cast(f16x8, ap[0]);
        f16x8 a1 = __builtin_bit_cast(f16x8, ap[4]);
        int rb = m0 + kg * 4;
#define MM1(n) { \
        f32x4 acc = {bias##n, bias##n, bias##n, bias##n}; \
        acc = __builtin_amdgcn_mfma_f32_16x16x32_f16(a0, b##n##_0, acc, 0, 0, 0); \
        acc = __builtin_amdgcn_mfma_f32_16x16x32_f16(a1, b##n##_1, acc, 0, 0, 0); \
        t16[(size_t)(rb + 0) * 128 + (n) * 16 + cl] = (_Float16)acc[0]; \
        t16[(size_t)(rb + 1) * 128 + (n) * 16 + cl] = (_Float16)acc[1]; \
        t16[(size_t)(rb + 2) * 128 + (n) * 16 + cl] = (_Float16)acc[2]; \
        t16[(size_t)(rb + 3) * 128 + (n) * 16 + cl] = (_Float16)acc[3]; \
        sum##n += (acc[0] + acc[1]) + (acc[2] + acc[3]); \
        sq##n  += (acc[0]*acc[0] + acc[1]*acc[1]) + (acc[2]*acc[2] + acc[3]*acc[3]); }
        MM1(0) MM1(1) MM1(2) MM1(3) MM1(4) MM1(5) MM1(6) MM1(7)
#undef MM1
    }
#define RD1(n) { \
        float s_ = sum##n, q_ = sq##n; \
        s_ += __shfl_xor(s_, 16); s_ += __shfl_xor(s_, 32); \
        q_ += __shfl_xor(q_, 16); q_ += __shfl_xor(q_, 32); \
        if (l < 16) { atomicAdd(&s1[(n) * 16 + l], s_); atomicAdd(&s1[128 + (n) * 16 + l], q_); } }
    RD1(0) RD1(1) RD1(2) RD1(3) RD1(4) RD1(5) RD1(6) RD1(7)
#undef RD1
}

// -------------------- MFMA mlp2 with fused fp32 BN+ReLU (R11-proven) -------------------
__global__ __launch_bounds__(256) void k_mlp2(const _Float16* __restrict__ t16,
                                              const _Float16* __restrict__ w2t,
                                              const float* __restrict__ b2,
                                              const float* __restrict__ s1,
                                              const float* __restrict__ bng,
                                              const float* __restrict__ bnb,
                                              _Float16* __restrict__ y16,
                                              float* __restrict__ s2) {
    int tid = threadIdx.x, l = tid & 63;
    int cl = l & 15, kg = l >> 4;
#define CO32(f) \
    float ca##f[8], cb##f[8]; \
    _Pragma("unroll") \
    for (int e = 0; e < 8; ++e) { \
        int k0 = (f) * 32 + kg * 8 + e; \
        float mu = s1[k0] * (1.f / N_NODES); \
        float va = s1[128 + k0] * (1.f / N_NODES) - mu * mu; \
        float a  = rsqrtf(va + 1e-5f) * bng[k0]; \
        ca##f[e] = a; \
        cb##f[e] = bnb[k0] - mu * a; }
    CO32(0) CO32(1) CO32(2) CO32(3)
#undef CO32
#define DB2(n) \
    f16x8 b##n##_0 = *(const f16x8*)&w2t[((n) * 16 + cl) * 128 +  0 + kg * 8]; \
    f16x8 b##n##_1 = *(const f16x8*)&w2t[((n) * 16 + cl) * 128 + 32 + kg * 8]; \
    f16x8 b##n##_2 = *(const f16x8*)&w2t[((n) * 16 + cl) * 128 + 64 + kg * 8]; \
    f16x8 b##n##_3 = *(const f16x8*)&w2t[((n) * 16 + cl) * 128 + 96 + kg * 8]; \
    float bias##n = b2[(n) * 16 + cl]; float sum##n = 0.f, sq##n = 0.f;
    DB2(0) DB2(1) DB2(2) DB2(3)
#undef DB2
    int wid = blockIdx.x * 4 + (tid >> 6);
    for (int t = wid; t < N_NODES / 16; t += gridDim.x * 4) {
        int m0 = t * 16;
        const uint4* ap = (const uint4*)(t16 + (size_t)(m0 + cl) * 128 + kg * 8);
        uint4 u0 = ap[0], u1 = ap[4], u2 = ap[8], u3 = ap[12];
#define TRU(u, f, q) { \
        __half2 hv = __builtin_bit_cast(__half2, u); \
        float v0 = fmaxf(fmaf(__low2float(hv),  ca##f[2*(q)],     cb##f[2*(q)]),     0.f); \
        float v1 = fmaxf(fmaf(__high2float(hv), ca##f[2*(q) + 1], cb##f[2*(q) + 1]), 0.f); \
        u = __builtin_bit_cast(unsigned, __floats2half2_rn(v0, v1)); }
#define TR(U, f) TRU(U.x, f, 0) TRU(U.y, f, 1) TRU(U.z, f, 2) TRU(U.w, f, 3)
        TR(u0, 0) TR(u1, 1) TR(u2, 2) TR(u3, 3)
#undef TR
#undef TRU
        f16x8 a0 = __builtin_bit_cast(f16x8, u0);
        f16x8 a1 = __builtin_bit_cast(f16x8, u1);
        f16x8 a2 = __builtin_bit_cast(f16x8, u2);
        f16x8 a3 = __builtin_bit_cast(f16x8, u3);
        int rb = m0 + kg * 4;
#define MM2(n) { \
        f32x4 acc = {bias##n, bias##n, bias##n, bias##n}; \
        acc = __builtin_amdgcn_mfma_f32_16x16x32_f16(a0, b##n##_0, acc, 0, 0, 0); \
        acc = __builtin_amdgcn_mfma_f32_16x16x32_f16(a1, b##n##_1, acc, 0, 0, 0); \
        acc = __builtin_amdgcn_mfma_f32_16x16x32_f16(a2, b##n##_2, acc, 0, 0, 0); \
        acc = __builtin_amdgcn_mfma_f32_16x16x32_f16(a3, b##n##_3, acc, 0, 0, 0); \
        y16[(size_t)(rb + 0) * 64 + (n) * 16 + cl] = (_Float16)acc[0]; \
        y16[(size_t)(rb + 1) * 64 + (n) * 16 + cl] = (_Float16)acc[1]; \
        y16[(size_t)(rb + 2) * 64 + (n) * 16 + cl] = (_Float16)acc[2]; \
        y16[(size_t)(rb + 3) * 64 + (n) * 16 + cl] = (_Float16)acc[3]; \
        sum##n += (acc[0] + acc[1]) + (acc[2] + acc[3]); \
        sq##n  += (acc[0]*acc[0] + acc[1]*acc[1]) + (acc[2]*acc[2] + acc[3]*acc[3]); }
        MM2(0) MM2(1) MM2(2) MM2(3)
#undef MM2
    }
#define RD2(n) { \
        float s_ = sum##n, q_ = sq##n; \
        s_ += __shfl_xor(s_, 16); s_ += __shfl_xor(s_, 32); \
        q_ += __shfl_xor(q_, 16); q_ += __shfl_xor(q_, 32); \
        if (l < 16) { atomicAdd(&s2[(n) * 16 + l], s_); atomicAdd(&s2[64 + (n) * 16 + l], q_); } }
    RD2(0) RD2(1) RD2(2) RD2(3)
#undef RD2
}

// -------------------- final outer BN (no relu): fp16 y -> fp32 out --------------------
__global__ __launch_bounds__(256) void k_bn2(const _Float16* __restrict__ y16,
                                             const float* __restrict__ s2,
                                             const float* __restrict__ g,
                                             const float* __restrict__ b,
                                             float* __restrict__ xout) {
    int idx = blockIdx.x * blockDim.x + threadIdx.x;   // N*8 groups of 8 ch
    if (idx >= N_NODES * 8) return;
    int c0 = (idx & 7) * 8;
    uint4 yin = ((const uint4*)y16)[idx];
    const unsigned* yp = &yin.x;
    float out[8];
#pragma unroll
    for (int q = 0; q < 4; ++q) {
        __half2 hv = __builtin_bit_cast(__half2, yp[q]);
        float v0 = __low2float(hv), v1 = __high2float(hv);
        int c = c0 + 2 * q;
        float mu0 = s2[c] * (1.f / N_NODES);
        float va0 = s2[64 + c] * (1.f / N_NODES) - mu0 * mu0;
        out[2 * q]     = (v0 - mu0) * rsqrtf(va0 + 1e-5f) * g[c] + b[c];
        float mu1 = s2[c + 1] * (1.f / N_NODES);
        float va1 = s2[64 + c + 1] * (1.f / N_NODES) - mu1 * mu1;
        out[2 * q + 1] = (v1 - mu1) * rsqrtf(va1 + 1e-5f) * g[c + 1] + b[c + 1];
    }
    float4* op = (float4*)(xout + (size_t)idx * 8);
    op[0] = make_float4(out[0], out[1], out[2], out[3]);
    op[1] = make_float4(out[4], out[5], out[6], out[7]);
}

extern "C" void kernel_launch(void* const* d_in, const int* in_sizes, int n_in,
                              void* d_out, int out_size, void* d_ws, size_t ws_size,
                              hipStream_t stream) {
    const float* z     = (const float*)d_in[0];
    const int*   batch = (const int*)  d_in[1];
    const int*   eidx  = (const int*)  d_in[2];
    const float* eattr = (const float*)d_in[3];
    const float* lin_w = (const float*)d_in[4];
    const float* lin_b = (const float*)d_in[5];
    const int* src = eidx;
    const int* dst = eidx + N_EDGES;

    char* ws = (char*)d_ws;
    size_t off = 0;
    auto alloc = [&](size_t bytes) -> void* {
        void* p = ws + off;
        off = (off + bytes + 255) & ~(size_t)255;
        return p;
    };
    float*    p        = (float*)   alloc((size_t)B_GRAPH * HID * 4);
    _Float16* bufA     = (_Float16*)alloc((size_t)N_NODES * 64 * 2);
    _Float16* bufB     = (_Float16*)alloc((size_t)N_NODES * 64 * 2);
    _Float16* agg16    = (_Float16*)alloc((size_t)N_NODES * 64 * 2);
    _Float16* t16      = (_Float16*)alloc((size_t)N_NODES * 128 * 2);
    _Float16* wtbuf    = (_Float16*)alloc((size_t)3 * 16384 * 2);
    int*      rowstart = (int*)     alloc((size_t)(N_NODES + 1) * 4);
    int*      cursor   = (int*)     alloc((size_t)(N_NODES + 1) * 4);  // doubles as counts
    int*      btot     = (int*)     alloc(64 * 4);
    int*      boff     = (int*)     alloc(65 * 4);
    int*      csr_src  = (int*)     alloc((size_t)N_EDGES * 4);
    __half2*  attr_h   = (__half2*) alloc((size_t)N_EDGES * 16 * 2);
    float*    stats    = (float*)   alloc((size_t)3 * 512 * 4);

    hipMemsetAsync(cursor, 0, (size_t)(N_NODES + 1) * 4, stream);

    k_setup<<<(N_EDGES + 255) / 256, 256, 0, stream>>>(
        dst, cursor, z, lin_w, lin_b, p,
        (const float*)d_in[6 + 0 * 10 + 2], (const float*)d_in[6 + 0 * 10 + 6],
        (const float*)d_in[6 + 1 * 10 + 2], (const float*)d_in[6 + 1 * 10 + 6],
        (const float*)d_in[6 + 2 * 10 + 2], (const float*)d_in[6 + 2 * 10 + 6],
        wtbuf, stats);
    k_scanA<<<NBLK_SCAN, 1024, 0, stream>>>(cursor, rowstart, btot);
    k_scanB<<<1, 64, 0, stream>>>(btot, boff);
    k_scanC<<<(N_NODES + 256) / 256, 256, 0, stream>>>(rowstart, boff, cursor);
    k_scatgath<<<(N_EDGES + 255) / 256, 256, 0, stream>>>(src, dst, eattr, cursor,
                                                          csr_src, attr_h, p, batch, bufA);

    const _Float16* IN[3]  = { bufA, bufB, bufA };
    _Float16*       OUT[3] = { bufB, bufA, bufB };
    for (int l = 0; l < 3; ++l) {
        const float* ew  = (const float*)d_in[6 + l * 10 + 0];
        const float* eb  = (const float*)d_in[6 + l * 10 + 1];
        const float* b1  = (const float*)d_in[6 + l * 10 + 3];
        const float* bng = (const float*)d_in[6 + l * 10 + 4];
        const float* bnb = (const float*)d_in[6 + l * 10 + 5];
        const float* b2  = (const float*)d_in[6 + l * 10 + 7];
        const _Float16* w1t = wtbuf + l * 16384;
        const _Float16* w2t = wtbuf + l * 16384 + 8192;
        float* s1 = stats + l * 512;          // [0:128] sum t, [128:256] sumsq t
        float* s2 = s1 + 256;                 // [0:64]  sum y, [64:128]  sumsq y
        const float* prev_s2 = (l == 0) ? nullptr : stats + (l - 1) * 512 + 256;
        const float* prev_g  = (l == 0) ? nullptr : (const float*)d_in[6 + (l - 1) * 10 + 8];
        const float* prev_b  = (l == 0) ? nullptr : (const float*)d_in[6 + (l - 1) * 10 + 9];
        float relu_neg = (l == 0) ? -1e30f : 0.f;

        k_edge<<<2048, 256, 0, stream>>>(IN[l], prev_s2, prev_g, prev_b, relu_neg,
                                         rowstart, csr_src, (const _Float16*)attr_h,
                                         ew, eb, agg16);
        k_mlp1<<<782, 256, 0, stream>>>(agg16, w1t, b1, t16, s1);
        k_mlp2<<<782, 256, 0, stream>>>(t16, w2t, b2, s1, bng, bnb, OUT[l], s2);
    }
    k_bn2<<<(N_NODES * 8 + 255) / 256, 256, 0, stream>>>(bufB, stats + 2 * 512 + 256,
                                                         (const float*)d_in[6 + 2 * 10 + 8],
                                                         (const float*)d_in[6 + 2 * 10 + 9],
                                                         (float*)d_out);
}

// Round 13
// 368.093 us; speedup vs baseline: 2.1601x; 2.1601x over previous
//
#include <hip/hip_runtime.h>
#include <hip/hip_fp16.h>

#define N_NODES 50000
#define N_EDGES 800000
#define B_GRAPH 256
#define IN_DIM  128
#define HID     64
#define NBLK_SCAN ((N_NODES + 1023) / 1024)   // 49

typedef _Float16 f16x8 __attribute__((ext_vector_type(8)));
typedef float    f32x4 __attribute__((ext_vector_type(4)));

// ---------- fused setup: histogram + z-latent + weight transposes + stats zero ----------
__global__ __launch_bounds__(256) void k_setup(const int* __restrict__ dst,
                                               int* __restrict__ counts,
                                               const float* __restrict__ z,
                                               const float* __restrict__ lw,
                                               const float* __restrict__ lb,
                                               float* __restrict__ p,
                                               const float* __restrict__ w1a,
                                               const float* __restrict__ w2a,
                                               const float* __restrict__ w1b,
                                               const float* __restrict__ w2b,
                                               const float* __restrict__ w1c,
                                               const float* __restrict__ w2c,
                                               _Float16* __restrict__ wtbuf,
                                               float* __restrict__ stats) {
    int idx = blockIdx.x * blockDim.x + threadIdx.x;   // grid covers N_EDGES
    if (idx < N_EDGES) atomicAdd(&counts[dst[idx]], 1);
    if (idx < 3 * 512) stats[idx] = 0.f;
    if (idx < 3 * 16384) {                              // weight transpose, 3 layers
        int l = idx >> 14, r = idx & 16383;
        const float* w1 = (l == 0) ? w1a : ((l == 1) ? w1b : w1c);
        const float* w2 = (l == 0) ? w2a : ((l == 1) ? w2b : w2c);
        _Float16* o = wtbuf + l * 16384;
        if (r < 8192) { int k = r >> 7, c = r & 127; o[c * 64 + k] = (_Float16)w1[r]; }
        else { int q = r - 8192; int k = q >> 6, c = q & 63; o[8192 + c * 128 + k] = (_Float16)w2[q]; }
    }
    if (idx < B_GRAPH * HID) {                          // p = relu(z @ lin_w + lin_b)
        int row = idx >> 6, c = idx & 63;
        float acc = lb[c];
        const float* zr = z + row * IN_DIM;
#pragma unroll 8
        for (int k = 0; k < IN_DIM; ++k) acc = fmaf(zr[k], lw[k * HID + c], acc);
        p[idx] = fmaxf(acc, 0.f);
    }
}

// -------------------- CSR scan (two-level) --------------------
__global__ __launch_bounds__(1024) void k_scanA(const int* __restrict__ counts,
                                                int* __restrict__ rowstart,
                                                int* __restrict__ btot) {
    __shared__ int wsum[16];
    int tid = threadIdx.x, lane = tid & 63, w = tid >> 6;
    int i = blockIdx.x * 1024 + tid;
    int v = (i < N_NODES) ? counts[i] : 0;
    int s = v;
#pragma unroll
    for (int off = 1; off < 64; off <<= 1) {
        int t = __shfl_up(s, off, 64);
        if (lane >= off) s += t;
    }
    if (lane == 63) wsum[w] = s;
    __syncthreads();
    if (w == 0) {
        int ws = (lane < 16) ? wsum[lane] : 0;
#pragma unroll
        for (int off = 1; off < 16; off <<= 1) {
            int t = __shfl_up(ws, off, 64);
            if (lane >= off) ws += t;
        }
        if (lane < 16) wsum[lane] = ws;
    }
    __syncthreads();
    int wbase = (w == 0) ? 0 : wsum[w - 1];
    if (i < N_NODES) rowstart[i] = wbase + s - v;
    if (tid == 0) btot[blockIdx.x] = wsum[15];
}

__global__ __launch_bounds__(64) void k_scanB(const int* __restrict__ btot,
                                              int* __restrict__ boff) {
    int lane = threadIdx.x;
    int v = (lane < NBLK_SCAN) ? btot[lane] : 0;
    int s = v;
#pragma unroll
    for (int off = 1; off < 64; off <<= 1) {
        int t = __shfl_up(s, off, 64);
        if (lane >= off) s += t;
    }
    if (lane < NBLK_SCAN) boff[lane] = s - v;
    if (lane == 63) boff[NBLK_SCAN] = s;
}

__global__ __launch_bounds__(256) void k_scanC(int* __restrict__ rowstart,
                                               const int* __restrict__ boff,
                                               int* __restrict__ cursor) {
    int i = blockIdx.x * blockDim.x + threadIdx.x;
    if (i < N_NODES) {
        int r = rowstart[i] + boff[i >> 10];
        rowstart[i] = r;
        cursor[i] = r;
    } else if (i == N_NODES) {
        rowstart[N_NODES] = boff[NBLK_SCAN];
    }
}

// ---------- fused: CSR scatter + packed fp16 attr + latent gather ----------
__global__ __launch_bounds__(256) void k_scatgath(const int* __restrict__ src,
                                                  const int* __restrict__ dst,
                                                  const float* __restrict__ ea,
                                                  int* __restrict__ cursor,
                                                  int* __restrict__ csr_src,
                                                  __half2* __restrict__ attr_h,
                                                  const float* __restrict__ p,
                                                  const int* __restrict__ batch,
                                                  _Float16* __restrict__ x0h) {
    int idx = blockIdx.x * blockDim.x + threadIdx.x;
    if (idx < N_EDGES) {
        int d = dst[idx];
        int pos = atomicAdd(&cursor[d], 1);
        csr_src[pos] = src[idx];
        const float4* s0 = (const float4*)(ea + (size_t)idx * 16);
        float4 f0 = s0[0], f1 = s0[1], f2 = s0[2], f3 = s0[3];
        uint4 u0, u1;
        u0.x = __builtin_bit_cast(unsigned, __floats2half2_rn(f0.x, f0.y));
        u0.y = __builtin_bit_cast(unsigned, __floats2half2_rn(f0.z, f0.w));
        u0.z = __builtin_bit_cast(unsigned, __floats2half2_rn(f1.x, f1.y));
        u0.w = __builtin_bit_cast(unsigned, __floats2half2_rn(f1.z, f1.w));
        u1.x = __builtin_bit_cast(unsigned, __floats2half2_rn(f2.x, f2.y));
        u1.y = __builtin_bit_cast(unsigned, __floats2half2_rn(f2.z, f2.w));
        u1.z = __builtin_bit_cast(unsigned, __floats2half2_rn(f3.x, f3.y));
        u1.w = __builtin_bit_cast(unsigned, __floats2half2_rn(f3.z, f3.w));
        uint4* op = (uint4*)(attr_h + (size_t)pos * 8);
        op[0] = u0;
        op[1] = u1;
    }
    if (idx < N_NODES * 16) {                           // x0h[n] = fp16(p[batch[n]])
        int n = idx >> 4, q = idx & 15;
        float4 v = ((const float4*)(p + batch[n] * 64))[q];
        uint2 u;
        u.x = __builtin_bit_cast(unsigned, __floats2half2_rn(v.x, v.y));
        u.y = __builtin_bit_cast(unsigned, __floats2half2_rn(v.z, v.w));
        ((uint2*)(x0h + (size_t)n * 64 + q * 4))[0] = u;
    }
}

// -------------------- edge pass: one wave per node, 8-edge chunks (R8/R11-proven) -------
__global__ __launch_bounds__(256) void k_edge(const _Float16* __restrict__ y,
                                              const float* __restrict__ s2,
                                              const float* __restrict__ bg,
                                              const float* __restrict__ bb,
                                              float relu_neg,
                                              const int* __restrict__ rowstart,
                                              const int* __restrict__ csr_src,
                                              const _Float16* __restrict__ attr_h,
                                              const float* __restrict__ ew,
                                              const float* __restrict__ eb,
                                              _Float16* __restrict__ agg16) {
    int tid = threadIdx.x, lane = tid & 63;
    __half2 rw2[8];
#pragma unroll
    for (int k = 0; k < 8; ++k)
        rw2[k] = __floats2half2_rn(ew[(2 * k) * 64 + lane], ew[(2 * k + 1) * 64 + lane]);
    float ebl = eb[lane];
    float sA = 1.f, sB = 0.f;
    if (s2) {
        float mu  = s2[lane] * (1.f / N_NODES);
        float var = s2[64 + lane] * (1.f / N_NODES) - mu * mu;
        sA = rsqrtf(var + 1e-5f) * bg[lane];
        sB = bb[lane] - mu * sA;
    }
    const __half2 hz = __float2half2_rn(0.f);
    int wave = blockIdx.x * 4 + (tid >> 6);
    int nw = gridDim.x * 4;
    for (int n0 = wave; n0 < N_NODES; n0 += nw) {
        int n = __builtin_amdgcn_readfirstlane(n0);
        int beg = rowstart[n], end = rowstart[n + 1];
        float xr = fmaxf(fmaf((float)y[(size_t)n * 64 + lane], sA, sB), relu_neg);
        float num = 0.f, den = 0.f;
        for (int i = beg; i < end; i += 8) {
            int lim = end - 1;
            int sv = csr_src[min(i + (lane & 7), lim)];
            float xs[8];
            uint4 ua[8], ub[8];
#pragma unroll
            for (int j = 0; j < 8; ++j) {
                int s = __builtin_amdgcn_readlane(sv, j);
                xs[j] = (float)y[(size_t)s * 64 + lane];
                int ej = min(i + j, lim);               // wave-uniform
                const uint4* ap = (const uint4*)(attr_h + (size_t)ej * 16);
                ua[j] = ap[0];
                ub[j] = ap[1];
            }
            int ns = end - i;
#pragma unroll
            for (int j = 0; j < 8; ++j) {
                if (j < ns) {
                    __half2 aE = hz, aO = hz;
                    aE = __hfma2(__builtin_bit_cast(__half2, ua[j].x), rw2[0], aE);
                    aO = __hfma2(__builtin_bit_cast(__half2, ua[j].y), rw2[1], aO);
                    aE = __hfma2(__builtin_bit_cast(__half2, ua[j].z), rw2[2], aE);
                    aO = __hfma2(__builtin_bit_cast(__half2, ua[j].w), rw2[3], aO);
                    aE = __hfma2(__builtin_bit_cast(__half2, ub[j].x), rw2[4], aE);
                    aO = __hfma2(__builtin_bit_cast(__half2, ub[j].y), rw2[5], aO);
                    aE = __hfma2(__builtin_bit_cast(__half2, ub[j].z), rw2[6], aE);
                    aO = __hfma2(__builtin_bit_cast(__half2, ub[j].w), rw2[7], aO);
                    float el = ebl + (__low2float(aE) + __high2float(aE))
                                   + (__low2float(aO) + __high2float(aO));
                    float xv = fmaxf(fmaf(xs[j], sA, sB), relu_neg);
                    float m  = fmaxf(xv + el, 0.f) + 1e-7f;
                    float e2 = __expf(m);
                    num = fmaf(m, e2, num);
                    den += e2;
                }
            }
        }
        agg16[(size_t)n * 64 + lane] = (_Float16)(num / (den + 1e-16f) + xr);
    }
}

// -------------------- MFMA mlp1: t16 = agg16 @ w1 + b1 ; block-reduced stats ------------
__global__ __launch_bounds__(256) void k_mlp1(const _Float16* __restrict__ agg16,
                                              const _Float16* __restrict__ w1t,
                                              const float* __restrict__ b1,
                                              _Float16* __restrict__ t16,
                                              float* __restrict__ s1) {
    __shared__ float red[4][256];
    int tid = threadIdx.x, l = tid & 63, w = tid >> 6;
    int cl = l & 15, kg = l >> 4;
#define DB1(n) \
    f16x8 b##n##_0 = *(const f16x8*)&w1t[((n) * 16 + cl) * 64 + kg * 8]; \
    f16x8 b##n##_1 = *(const f16x8*)&w1t[((n) * 16 + cl) * 64 + 32 + kg * 8]; \
    float bias##n = b1[(n) * 16 + cl]; float sum##n = 0.f, sq##n = 0.f;
    DB1(0) DB1(1) DB1(2) DB1(3) DB1(4) DB1(5) DB1(6) DB1(7)
#undef DB1
    int wid = blockIdx.x * 4 + w;
    for (int t = wid; t < N_NODES / 16; t += gridDim.x * 4) {
        int m0 = t * 16;
        const uint4* ap = (const uint4*)(agg16 + (size_t)(m0 + cl) * 64 + kg * 8);
        f16x8 a0 = __builtin_bit_cast(f16x8, ap[0]);
        f16x8 a1 = __builtin_bit_cast(f16x8, ap[4]);
        int rb = m0 + kg * 4;
#define MM1(n) { \
        f32x4 acc = {bias##n, bias##n, bias##n, bias##n}; \
        acc = __builtin_amdgcn_mfma_f32_16x16x32_f16(a0, b##n##_0, acc, 0, 0, 0); \
        acc = __builtin_amdgcn_mfma_f32_16x16x32_f16(a1, b##n##_1, acc, 0, 0, 0); \
        t16[(size_t)(rb + 0) * 128 + (n) * 16 + cl] = (_Float16)acc[0]; \
        t16[(size_t)(rb + 1) * 128 + (n) * 16 + cl] = (_Float16)acc[1]; \
        t16[(size_t)(rb + 2) * 128 + (n) * 16 + cl] = (_Float16)acc[2]; \
        t16[(size_t)(rb + 3) * 128 + (n) * 16 + cl] = (_Float16)acc[3]; \
        sum##n += (acc[0] + acc[1]) + (acc[2] + acc[3]); \
        sq##n  += (acc[0]*acc[0] + acc[1]*acc[1]) + (acc[2]*acc[2] + acc[3]*acc[3]); }
        MM1(0) MM1(1) MM1(2) MM1(3) MM1(4) MM1(5) MM1(6) MM1(7)
#undef MM1
    }
#define RD1(n) { \
        float s_ = sum##n, q_ = sq##n; \
        s_ += __shfl_xor(s_, 16); s_ += __shfl_xor(s_, 32); \
        q_ += __shfl_xor(q_, 16); q_ += __shfl_xor(q_, 32); \
        if (l < 16) { red[w][(n) * 16 + l] = s_; red[w][128 + (n) * 16 + l] = q_; } }
    RD1(0) RD1(1) RD1(2) RD1(3) RD1(4) RD1(5) RD1(6) RD1(7)
#undef RD1
    __syncthreads();
    if (tid < 256) {
        float v = red[0][tid] + red[1][tid] + red[2][tid] + red[3][tid];
        atomicAdd(&s1[tid], v);       // one atomic per channel per block
    }
}

// -------------------- MFMA mlp2 + fused fp32 BN+ReLU ; block-reduced stats -------------
__global__ __launch_bounds__(256) void k_mlp2(const _Float16* __restrict__ t16,
                                              const _Float16* __restrict__ w2t,
                                              const float* __restrict__ b2,
                                              const float* __restrict__ s1,
                                              const float* __restrict__ bng,
                                              const float* __restrict__ bnb,
                                              _Float16* __restrict__ y16,
                                              float* __restrict__ s2) {
    __shared__ float red[4][128];
    int tid = threadIdx.x, l = tid & 63, w = tid >> 6;
    int cl = l & 15, kg = l >> 4;
#define CO32(f) \
    float ca##f[8], cb##f[8]; \
    _Pragma("unroll") \
    for (int e = 0; e < 8; ++e) { \
        int k0 = (f) * 32 + kg * 8 + e; \
        float mu = s1[k0] * (1.f / N_NODES); \
        float va = s1[128 + k0] * (1.f / N_NODES) - mu * mu; \
        float a  = rsqrtf(va + 1e-5f) * bng[k0]; \
        ca##f[e] = a; \
        cb##f[e] = bnb[k0] - mu * a; }
    CO32(0) CO32(1) CO32(2) CO32(3)
#undef CO32
#define DB2(n) \
    f16x8 b##n##_0 = *(const f16x8*)&w2t[((n) * 16 + cl) * 128 +  0 + kg * 8]; \
    f16x8 b##n##_1 = *(const f16x8*)&w2t[((n) * 16 + cl) * 128 + 32 + kg * 8]; \
    f16x8 b##n##_2 = *(const f16x8*)&w2t[((n) * 16 + cl) * 128 + 64 + kg * 8]; \
    f16x8 b##n##_3 = *(const f16x8*)&w2t[((n) * 16 + cl) * 128 + 96 + kg * 8]; \
    float bias##n = b2[(n) * 16 + cl]; float sum##n = 0.f, sq##n = 0.f;
    DB2(0) DB2(1) DB2(2) DB2(3)
#undef DB2
    int wid = blockIdx.x * 4 + w;
    for (int t = wid; t < N_NODES / 16; t += gridDim.x * 4) {
        int m0 = t * 16;
        const uint4* ap = (const uint4*)(t16 + (size_t)(m0 + cl) * 128 + kg * 8);
        uint4 u0 = ap[0], u1 = ap[4], u2 = ap[8], u3 = ap[12];
#define TRU(u, f, q) { \
        __half2 hv = __builtin_bit_cast(__half2, u); \
        float v0 = fmaxf(fmaf(__low2float(hv),  ca##f[2*(q)],     cb##f[2*(q)]),     0.f); \
        float v1 = fmaxf(fmaf(__high2float(hv), ca##f[2*(q) + 1], cb##f[2*(q) + 1]), 0.f); \
        u = __builtin_bit_cast(unsigned, __floats2half2_rn(v0, v1)); }
#define TR(U, f) TRU(U.x, f, 0) TRU(U.y, f, 1) TRU(U.z, f, 2) TRU(U.w, f, 3)
        TR(u0, 0) TR(u1, 1) TR(u2, 2) TR(u3, 3)
#undef TR
#undef TRU
        f16x8 a0 = __builtin_bit_cast(f16x8, u0);
        f16x8 a1 = __builtin_bit_cast(f16x8, u1);
        f16x8 a2 = __builtin_bit_cast(f16x8, u2);
        f16x8 a3 = __builtin_bit_cast(f16x8, u3);
        int rb = m0 + kg * 4;
#define MM2(n) { \
        f32x4 acc = {bias##n, bias##n, bias##n, bias##n}; \
        acc = __builtin_amdgcn_mfma_f32_16x16x32_f16(a0, b##n##_0, acc, 0, 0, 0); \
        acc = __builtin_amdgcn_mfma_f32_16x16x32_f16(a1, b##n##_1, acc, 0, 0, 0); \
        acc = __builtin_amdgcn_mfma_f32_16x16x32_f16(a2, b##n##_2, acc, 0, 0, 0); \
        acc = __builtin_amdgcn_mfma_f32_16x16x32_f16(a3, b##n##_3, acc, 0, 0, 0); \
        y16[(size_t)(rb + 0) * 64 + (n) * 16 + cl] = (_Float16)acc[0]; \
        y16[(size_t)(rb + 1) * 64 + (n) * 16 + cl] = (_Float16)acc[1]; \
        y16[(size_t)(rb + 2) * 64 + (n) * 16 + cl] = (_Float16)acc[2]; \
        y16[(size_t)(rb + 3) * 64 + (n) * 16 + cl] = (_Float16)acc[3]; \
        sum##n += (acc[0] + acc[1]) + (acc[2] + acc[3]); \
        sq##n  += (acc[0]*acc[0] + acc[1]*acc[1]) + (acc[2]*acc[2] + acc[3]*acc[3]); }
        MM2(0) MM2(1) MM2(2) MM2(3)
#undef MM2
    }
#define RD2(n) { \
        float s_ = sum##n, q_ = sq##n; \
        s_ += __shfl_xor(s_, 16); s_ += __shfl_xor(s_, 32); \
        q_ += __shfl_xor(q_, 16); q_ += __shfl_xor(q_, 32); \
        if (l < 16) { red[w][(n) * 16 + l] = s_; red[w][64 + (n) * 16 + l] = q_; } }
    RD2(0) RD2(1) RD2(2) RD2(3)
#undef RD2
    __syncthreads();
    if (tid < 128) {
        float v = red[0][tid] + red[1][tid] + red[2][tid] + red[3][tid];
        atomicAdd(&s2[tid], v);       // one atomic per channel per block
    }
}

// -------------------- final outer BN (no relu): fp16 y -> fp32 out --------------------
__global__ __launch_bounds__(256) void k_bn2(const _Float16* __restrict__ y16,
                                             const float* __restrict__ s2,
                                             const float* __restrict__ g,
                                             const float* __restrict__ b,
                                             float* __restrict__ xout) {
    int idx = blockIdx.x * blockDim.x + threadIdx.x;   // N*8 groups of 8 ch
    if (idx >= N_NODES * 8) return;
    int c0 = (idx & 7) * 8;
    uint4 yin = ((const uint4*)y16)[idx];
    const unsigned* yp = &yin.x;
    float out[8];
#pragma unroll
    for (int q = 0; q < 4; ++q) {
        __half2 hv = __builtin_bit_cast(__half2, yp[q]);
        float v0 = __low2float(hv), v1 = __high2float(hv);
        int c = c0 + 2 * q;
        float mu0 = s2[c] * (1.f / N_NODES);
        float va0 = s2[64 + c] * (1.f / N_NODES) - mu0 * mu0;
        out[2 * q]     = (v0 - mu0) * rsqrtf(va0 + 1e-5f) * g[c] + b[c];
        float mu1 = s2[c + 1] * (1.f / N_NODES);
        float va1 = s2[64 + c + 1] * (1.f / N_NODES) - mu1 * mu1;
        out[2 * q + 1] = (v1 - mu1) * rsqrtf(va1 + 1e-5f) * g[c + 1] + b[c + 1];
    }
    float4* op = (float4*)(xout + (size_t)idx * 8);
    op[0] = make_float4(out[0], out[1], out[2], out[3]);
    op[1] = make_float4(out[4], out[5], out[6], out[7]);
}

extern "C" void kernel_launch(void* const* d_in, const int* in_sizes, int n_in,
                              void* d_out, int out_size, void* d_ws, size_t ws_size,
                              hipStream_t stream) {
    const float* z     = (const float*)d_in[0];
    const int*   batch = (const int*)  d_in[1];
    const int*   eidx  = (const int*)  d_in[2];
    const float* eattr = (const float*)d_in[3];
    const float* lin_w = (const float*)d_in[4];
    const float* lin_b = (const float*)d_in[5];
    const int* src = eidx;
    const int* dst = eidx + N_EDGES;

    char* ws = (char*)d_ws;
    size_t off = 0;
    auto alloc = [&](size_t bytes) -> void* {
        void* p = ws + off;
        off = (off + bytes + 255) & ~(size_t)255;
        return p;
    };
    float*    p        = (float*)   alloc((size_t)B_GRAPH * HID * 4);
    _Float16* bufA     = (_Float16*)alloc((size_t)N_NODES * 64 * 2);
    _Float16* bufB     = (_Float16*)alloc((size_t)N_NODES * 64 * 2);
    _Float16* agg16    = (_Float16*)alloc((size_t)N_NODES * 64 * 2);
    _Float16* t16      = (_Float16*)alloc((size_t)N_NODES * 128 * 2);
    _Float16* wtbuf    = (_Float16*)alloc((size_t)3 * 16384 * 2);
    int*      rowstart = (int*)     alloc((size_t)(N_NODES + 1) * 4);
    int*      cursor   = (int*)     alloc((size_t)(N_NODES + 1) * 4);  // doubles as counts
    int*      btot     = (int*)     alloc(64 * 4);
    int*      boff     = (int*)     alloc(65 * 4);
    int*      csr_src  = (int*)     alloc((size_t)N_EDGES * 4);
    __half2*  attr_h   = (__half2*) alloc((size_t)N_EDGES * 16 * 2);
    float*    stats    = (float*)   alloc((size_t)3 * 512 * 4);

    hipMemsetAsync(cursor, 0, (size_t)(N_NODES + 1) * 4, stream);

    k_setup<<<(N_EDGES + 255) / 256, 256, 0, stream>>>(
        dst, cursor, z, lin_w, lin_b, p,
        (const float*)d_in[6 + 0 * 10 + 2], (const float*)d_in[6 + 0 * 10 + 6],
        (const float*)d_in[6 + 1 * 10 + 2], (const float*)d_in[6 + 1 * 10 + 6],
        (const float*)d_in[6 + 2 * 10 + 2], (const float*)d_in[6 + 2 * 10 + 6],
        wtbuf, stats);
    k_scanA<<<NBLK_SCAN, 1024, 0, stream>>>(cursor, rowstart, btot);
    k_scanB<<<1, 64, 0, stream>>>(btot, boff);
    k_scanC<<<(N_NODES + 256) / 256, 256, 0, stream>>>(rowstart, boff, cursor);
    k_scatgath<<<(N_EDGES + 255) / 256, 256, 0, stream>>>(src, dst, eattr, cursor,
                                                          csr_src, attr_h, p, batch, bufA);

    const _Float16* IN[3]  = { bufA, bufB, bufA };
    _Float16*       OUT[3] = { bufB, bufA, bufB };
    for (int l = 0; l < 3; ++l) {
        const float* ew  = (const float*)d_in[6 + l * 10 + 0];
        const float* eb  = (const float*)d_in[6 + l * 10 + 1];
        const float* b1  = (const float*)d_in[6 + l * 10 + 3];
        const float* bng = (const float*)d_in[6 + l * 10 + 4];
        const float* bnb = (const float*)d_in[6 + l * 10 + 5];
        const float* b2  = (const float*)d_in[6 + l * 10 + 7];
        const _Float16* w1t = wtbuf + l * 16384;
        const _Float16* w2t = wtbuf + l * 16384 + 8192;
        float* s1 = stats + l * 512;          // [0:128] sum t, [128:256] sumsq t
        float* s2 = s1 + 256;                 // [0:64]  sum y, [64:128]  sumsq y
        const float* prev_s2 = (l == 0) ? nullptr : stats + (l - 1) * 512 + 256;
        const float* prev_g  = (l == 0) ? nullptr : (const float*)d_in[6 + (l - 1) * 10 + 8];
        const float* prev_b  = (l == 0) ? nullptr : (const float*)d_in[6 + (l - 1) * 10 + 9];
        float relu_neg = (l == 0) ? -1e30f : 0.f;

        k_edge<<<2048, 256, 0, stream>>>(IN[l], prev_s2, prev_g, prev_b, relu_neg,
                                         rowstart, csr_src, (const _Float16*)attr_h,
                                         ew, eb, agg16);
        k_mlp1<<<128, 256, 0, stream>>>(agg16, w1t, b1, t16, s1);
        k_mlp2<<<128, 256, 0, stream>>>(t16, w2t, b2, s1, bng, bnb, OUT[l], s2);
    }
    k_bn2<<<(N_NODES * 8 + 255) / 256, 256, 0, stream>>>(bufB, stats + 2 * 512 + 256,
                                                         (const float*)d_in[6 + 2 * 10 + 8],
                                                         (const float*)d_in[6 + 2 * 10 + 9],
                                                         (float*)d_out);
}

// Round 14
// 347.902 us; speedup vs baseline: 2.2855x; 1.0580x over previous
//
#include <hip/hip_runtime.h>
#include <hip/hip_fp16.h>

#define N_NODES 50000
#define N_EDGES 800000
#define B_GRAPH 256
#define IN_DIM  128
#define HID     64
#define NBLK_SCAN ((N_NODES + 1023) / 1024)   // 49

typedef _Float16 f16x8 __attribute__((ext_vector_type(8)));
typedef _Float16 f16x2 __attribute__((ext_vector_type(2)));
typedef float    f32x4 __attribute__((ext_vector_type(4)));

// ---------- fused setup: histogram + z-latent + weight transposes + stats zero ----------
__global__ __launch_bounds__(256) void k_setup(const int* __restrict__ dst,
                                               int* __restrict__ counts,
                                               const float* __restrict__ z,
                                               const float* __restrict__ lw,
                                               const float* __restrict__ lb,
                                               float* __restrict__ p,
                                               const float* __restrict__ w1a,
                                               const float* __restrict__ w2a,
                                               const float* __restrict__ w1b,
                                               const float* __restrict__ w2b,
                                               const float* __restrict__ w1c,
                                               const float* __restrict__ w2c,
                                               _Float16* __restrict__ wtbuf,
                                               float* __restrict__ stats) {
    int idx = blockIdx.x * blockDim.x + threadIdx.x;   // grid covers N_EDGES
    if (idx < N_EDGES) atomicAdd(&counts[dst[idx]], 1);
    if (idx < 3 * 512) stats[idx] = 0.f;
    if (idx < 3 * 16384) {                              // weight transpose, 3 layers
        int l = idx >> 14, r = idx & 16383;
        const float* w1 = (l == 0) ? w1a : ((l == 1) ? w1b : w1c);
        const float* w2 = (l == 0) ? w2a : ((l == 1) ? w2b : w2c);
        _Float16* o = wtbuf + l * 16384;
        if (r < 8192) { int k = r >> 7, c = r & 127; o[c * 64 + k] = (_Float16)w1[r]; }
        else { int q = r - 8192; int k = q >> 6, c = q & 63; o[8192 + c * 128 + k] = (_Float16)w2[q]; }
    }
    if (idx < B_GRAPH * HID) {                          // p = relu(z @ lin_w + lin_b)
        int row = idx >> 6, c = idx & 63;
        float acc = lb[c];
        const float* zr = z + row * IN_DIM;
#pragma unroll 8
        for (int k = 0; k < IN_DIM; ++k) acc = fmaf(zr[k], lw[k * HID + c], acc);
        p[idx] = fmaxf(acc, 0.f);
    }
}

// -------------------- CSR scan (two-level) --------------------
__global__ __launch_bounds__(1024) void k_scanA(const int* __restrict__ counts,
                                                int* __restrict__ rowstart,
                                                int* __restrict__ btot) {
    __shared__ int wsum[16];
    int tid = threadIdx.x, lane = tid & 63, w = tid >> 6;
    int i = blockIdx.x * 1024 + tid;
    int v = (i < N_NODES) ? counts[i] : 0;
    int s = v;
#pragma unroll
    for (int off = 1; off < 64; off <<= 1) {
        int t = __shfl_up(s, off, 64);
        if (lane >= off) s += t;
    }
    if (lane == 63) wsum[w] = s;
    __syncthreads();
    if (w == 0) {
        int ws = (lane < 16) ? wsum[lane] : 0;
#pragma unroll
        for (int off = 1; off < 16; off <<= 1) {
            int t = __shfl_up(ws, off, 64);
            if (lane >= off) ws += t;
        }
        if (lane < 16) wsum[lane] = ws;
    }
    __syncthreads();
    int wbase = (w == 0) ? 0 : wsum[w - 1];
    if (i < N_NODES) rowstart[i] = wbase + s - v;
    if (tid == 0) btot[blockIdx.x] = wsum[15];
}

__global__ __launch_bounds__(64) void k_scanB(const int* __restrict__ btot,
                                              int* __restrict__ boff) {
    int lane = threadIdx.x;
    int v = (lane < NBLK_SCAN) ? btot[lane] : 0;
    int s = v;
#pragma unroll
    for (int off = 1; off < 64; off <<= 1) {
        int t = __shfl_up(s, off, 64);
        if (lane >= off) s += t;
    }
    if (lane < NBLK_SCAN) boff[lane] = s - v;
    if (lane == 63) boff[NBLK_SCAN] = s;
}

__global__ __launch_bounds__(256) void k_scanC(int* __restrict__ rowstart,
                                               const int* __restrict__ boff,
                                               int* __restrict__ cursor) {
    int i = blockIdx.x * blockDim.x + threadIdx.x;
    if (i < N_NODES) {
        int r = rowstart[i] + boff[i >> 10];
        rowstart[i] = r;
        cursor[i] = r;
    } else if (i == N_NODES) {
        rowstart[N_NODES] = boff[NBLK_SCAN];
    }
}

// ---------- fused: CSR scatter + packed fp16 attr + latent gather ----------
__global__ __launch_bounds__(256) void k_scatgath(const int* __restrict__ src,
                                                  const int* __restrict__ dst,
                                                  const float* __restrict__ ea,
                                                  int* __restrict__ cursor,
                                                  int* __restrict__ csr_src,
                                                  __half2* __restrict__ attr_h,
                                                  const float* __restrict__ p,
                                                  const int* __restrict__ batch,
                                                  _Float16* __restrict__ x0h) {
    int idx = blockIdx.x * blockDim.x + threadIdx.x;
    if (idx < N_EDGES) {
        int d = dst[idx];
        int pos = atomicAdd(&cursor[d], 1);
        csr_src[pos] = src[idx];
        const float4* s0 = (const float4*)(ea + (size_t)idx * 16);
        float4 f0 = s0[0], f1 = s0[1], f2 = s0[2], f3 = s0[3];
        uint4 u0, u1;
        u0.x = __builtin_bit_cast(unsigned, __floats2half2_rn(f0.x, f0.y));
        u0.y = __builtin_bit_cast(unsigned, __floats2half2_rn(f0.z, f0.w));
        u0.z = __builtin_bit_cast(unsigned, __floats2half2_rn(f1.x, f1.y));
        u0.w = __builtin_bit_cast(unsigned, __floats2half2_rn(f1.z, f1.w));
        u1.x = __builtin_bit_cast(unsigned, __floats2half2_rn(f2.x, f2.y));
        u1.y = __builtin_bit_cast(unsigned, __floats2half2_rn(f2.z, f2.w));
        u1.z = __builtin_bit_cast(unsigned, __floats2half2_rn(f3.x, f3.y));
        u1.w = __builtin_bit_cast(unsigned, __floats2half2_rn(f3.z, f3.w));
        uint4* op = (uint4*)(attr_h + (size_t)pos * 8);
        op[0] = u0;
        op[1] = u1;
    }
    if (idx < N_NODES * 16) {                           // x0h[n] = fp16(p[batch[n]])
        int n = idx >> 4, q = idx & 15;
        float4 v = ((const float4*)(p + batch[n] * 64))[q];
        uint2 u;
        u.x = __builtin_bit_cast(unsigned, __floats2half2_rn(v.x, v.y));
        u.y = __builtin_bit_cast(unsigned, __floats2half2_rn(v.z, v.w));
        ((uint2*)(x0h + (size_t)n * 64 + q * 4))[0] = u;
    }
}

// ---------- edge pass: one wave per node, 8-edge chunks; fdot2 edge-linear ----------
// v_dot2_f32_f16: fp16x2 dot with fp32 accumulate — replaces hfma2+unpack chain.
__global__ __launch_bounds__(256) void k_edge(const _Float16* __restrict__ y,
                                              const float* __restrict__ s2,
                                              const float* __restrict__ bg,
                                              const float* __restrict__ bb,
                                              float relu_neg,
                                              const int* __restrict__ rowstart,
                                              const int* __restrict__ csr_src,
                                              const _Float16* __restrict__ attr_h,
                                              const float* __restrict__ ew,
                                              const float* __restrict__ eb,
                                              _Float16* __restrict__ agg16) {
    int tid = threadIdx.x, lane = tid & 63;
    f16x2 rw[8];
#pragma unroll
    for (int k = 0; k < 8; ++k) {
        f16x2 t;
        t.x = (_Float16)ew[(2 * k) * 64 + lane];
        t.y = (_Float16)ew[(2 * k + 1) * 64 + lane];
        rw[k] = t;
    }
    float ebl = eb[lane];
    float sA = 1.f, sB = 0.f;
    if (s2) {
        float mu  = s2[lane] * (1.f / N_NODES);
        float var = s2[64 + lane] * (1.f / N_NODES) - mu * mu;
        sA = rsqrtf(var + 1e-5f) * bg[lane];
        sB = bb[lane] - mu * sA;
    }
    int wave = blockIdx.x * 4 + (tid >> 6);
    int nw = gridDim.x * 4;
    for (int n0 = wave; n0 < N_NODES; n0 += nw) {
        int n = __builtin_amdgcn_readfirstlane(n0);
        int beg = rowstart[n], end = rowstart[n + 1];
        int lim = end - 1;
        float xr = fmaxf(fmaf((float)y[(size_t)n * 64 + lane], sA, sB), relu_neg);
        float num = 0.f, den = 0.f;
        int sv = csr_src[min(beg + (lane & 7), lim)];   // prefetched first chunk
        for (int i = beg; i < end; i += 8) {
            int sv_cur = sv;
            int inext = i + 8;
            if (inext < end) sv = csr_src[min(inext + (lane & 7), lim)];
            float xs[8];
            uint4 ua[8], ub[8];
#pragma unroll
            for (int j = 0; j < 8; ++j) {
                int s = __builtin_amdgcn_readlane(sv_cur, j);
                xs[j] = (float)y[(size_t)s * 64 + lane];
                int ej = min(i + j, lim);               // wave-uniform -> s_load
                const uint4* ap = (const uint4*)(attr_h + (size_t)ej * 16);
                ua[j] = ap[0];
                ub[j] = ap[1];
            }
            int ns = end - i;
#pragma unroll
            for (int j = 0; j < 8; ++j) {
                if (j < ns) {
                    float el = ebl;
                    el = __builtin_amdgcn_fdot2(__builtin_bit_cast(f16x2, ua[j].x), rw[0], el, false);
                    el = __builtin_amdgcn_fdot2(__builtin_bit_cast(f16x2, ua[j].y), rw[1], el, false);
                    el = __builtin_amdgcn_fdot2(__builtin_bit_cast(f16x2, ua[j].z), rw[2], el, false);
                    el = __builtin_amdgcn_fdot2(__builtin_bit_cast(f16x2, ua[j].w), rw[3], el, false);
                    el = __builtin_amdgcn_fdot2(__builtin_bit_cast(f16x2, ub[j].x), rw[4], el, false);
                    el = __builtin_amdgcn_fdot2(__builtin_bit_cast(f16x2, ub[j].y), rw[5], el, false);
                    el = __builtin_amdgcn_fdot2(__builtin_bit_cast(f16x2, ub[j].z), rw[6], el, false);
                    el = __builtin_amdgcn_fdot2(__builtin_bit_cast(f16x2, ub[j].w), rw[7], el, false);
                    float xv = fmaxf(fmaf(xs[j], sA, sB), relu_neg);
                    float m  = fmaxf(xv + el, 0.f) + 1e-7f;
                    float e2 = __expf(m);
                    num = fmaf(m, e2, num);
                    den += e2;
                }
            }
        }
        agg16[(size_t)n * 64 + lane] = (_Float16)(num / (den + 1e-16f) + xr);
    }
}

// -------------------- MFMA mlp1: t16 = agg16 @ w1 + b1 ; block-reduced stats ------------
__global__ __launch_bounds__(256) void k_mlp1(const _Float16* __restrict__ agg16,
                                              const _Float16* __restrict__ w1t,
                                              const float* __restrict__ b1,
                                              _Float16* __restrict__ t16,
                                              float* __restrict__ s1) {
    __shared__ float red[4][256];
    int tid = threadIdx.x, l = tid & 63, w = tid >> 6;
    int cl = l & 15, kg = l >> 4;
#define DB1(n) \
    f16x8 b##n##_0 = *(const f16x8*)&w1t[((n) * 16 + cl) * 64 + kg * 8]; \
    f16x8 b##n##_1 = *(const f16x8*)&w1t[((n) * 16 + cl) * 64 + 32 + kg * 8]; \
    float bias##n = b1[(n) * 16 + cl]; float sum##n = 0.f, sq##n = 0.f;
    DB1(0) DB1(1) DB1(2) DB1(3) DB1(4) DB1(5) DB1(6) DB1(7)
#undef DB1
    int wid = blockIdx.x * 4 + w;
    for (int t = wid; t < N_NODES / 16; t += gridDim.x * 4) {
        int m0 = t * 16;
        const uint4* ap = (const uint4*)(agg16 + (size_t)(m0 + cl) * 64 + kg * 8);
        f16x8 a0 = __builtin_bit_cast(f16x8, ap[0]);
        f16x8 a1 = __builtin_bit_cast(f16x8, ap[4]);
        int rb = m0 + kg * 4;
#define MM1(n) { \
        f32x4 acc = {bias##n, bias##n, bias##n, bias##n}; \
        acc = __builtin_amdgcn_mfma_f32_16x16x32_f16(a0, b##n##_0, acc, 0, 0, 0); \
        acc = __builtin_amdgcn_mfma_f32_16x16x32_f16(a1, b##n##_1, acc, 0, 0, 0); \
        t16[(size_t)(rb + 0) * 128 + (n) * 16 + cl] = (_Float16)acc[0]; \
        t16[(size_t)(rb + 1) * 128 + (n) * 16 + cl] = (_Float16)acc[1]; \
        t16[(size_t)(rb + 2) * 128 + (n) * 16 + cl] = (_Float16)acc[2]; \
        t16[(size_t)(rb + 3) * 128 + (n) * 16 + cl] = (_Float16)acc[3]; \
        sum##n += (acc[0] + acc[1]) + (acc[2] + acc[3]); \
        sq##n  += (acc[0]*acc[0] + acc[1]*acc[1]) + (acc[2]*acc[2] + acc[3]*acc[3]); }
        MM1(0) MM1(1) MM1(2) MM1(3) MM1(4) MM1(5) MM1(6) MM1(7)
#undef MM1
    }
#define RD1(n) { \
        float s_ = sum##n, q_ = sq##n; \
        s_ += __shfl_xor(s_, 16); s_ += __shfl_xor(s_, 32); \
        q_ += __shfl_xor(q_, 16); q_ += __shfl_xor(q_, 32); \
        if (l < 16) { red[w][(n) * 16 + l] = s_; red[w][128 + (n) * 16 + l] = q_; } }
    RD1(0) RD1(1) RD1(2) RD1(3) RD1(4) RD1(5) RD1(6) RD1(7)
#undef RD1
    __syncthreads();
    if (tid < 256) {
        float v = red[0][tid] + red[1][tid] + red[2][tid] + red[3][tid];
        atomicAdd(&s1[tid], v);       // one atomic per channel per block
    }
}

// -------------------- MFMA mlp2 + fused fp32 BN+ReLU ; block-reduced stats -------------
__global__ __launch_bounds__(256) void k_mlp2(const _Float16* __restrict__ t16,
                                              const _Float16* __restrict__ w2t,
                                              const float* __restrict__ b2,
                                              const float* __restrict__ s1,
                                              const float* __restrict__ bng,
                                              const float* __restrict__ bnb,
                                              _Float16* __restrict__ y16,
                                              float* __restrict__ s2) {
    __shared__ float red[4][128];
    int tid = threadIdx.x, l = tid & 63, w = tid >> 6;
    int cl = l & 15, kg = l >> 4;
#define CO32(f) \
    float ca##f[8], cb##f[8]; \
    _Pragma("unroll") \
    for (int e = 0; e < 8; ++e) { \
        int k0 = (f) * 32 + kg * 8 + e; \
        float mu = s1[k0] * (1.f / N_NODES); \
        float va = s1[128 + k0] * (1.f / N_NODES) - mu * mu; \
        float a  = rsqrtf(va + 1e-5f) * bng[k0]; \
        ca##f[e] = a; \
        cb##f[e] = bnb[k0] - mu * a; }
    CO32(0) CO32(1) CO32(2) CO32(3)
#undef CO32
#define DB2(n) \
    f16x8 b##n##_0 = *(const f16x8*)&w2t[((n) * 16 + cl) * 128 +  0 + kg * 8]; \
    f16x8 b##n##_1 = *(const f16x8*)&w2t[((n) * 16 + cl) * 128 + 32 + kg * 8]; \
    f16x8 b##n##_2 = *(const f16x8*)&w2t[((n) * 16 + cl) * 128 + 64 + kg * 8]; \
    f16x8 b##n##_3 = *(const f16x8*)&w2t[((n) * 16 + cl) * 128 + 96 + kg * 8]; \
    float bias##n = b2[(n) * 16 + cl]; float sum##n = 0.f, sq##n = 0.f;
    DB2(0) DB2(1) DB2(2) DB2(3)
#undef DB2
    int wid = blockIdx.x * 4 + w;
    for (int t = wid; t < N_NODES / 16; t += gridDim.x * 4) {
        int m0 = t * 16;
        const uint4* ap = (const uint4*)(t16 + (size_t)(m0 + cl) * 128 + kg * 8);
        uint4 u0 = ap[0], u1 = ap[4], u2 = ap[8], u3 = ap[12];
#define TRU(u, f, q) { \
        __half2 hv = __builtin_bit_cast(__half2, u); \
        float v0 = fmaxf(fmaf(__low2float(hv),  ca##f[2*(q)],     cb##f[2*(q)]),     0.f); \
        float v1 = fmaxf(fmaf(__high2float(hv), ca##f[2*(q) + 1], cb##f[2*(q) + 1]), 0.f); \
        u = __builtin_bit_cast(unsigned, __floats2half2_rn(v0, v1)); }
#define TR(U, f) TRU(U.x, f, 0) TRU(U.y, f, 1) TRU(U.z, f, 2) TRU(U.w, f, 3)
        TR(u0, 0) TR(u1, 1) TR(u2, 2) TR(u3, 3)
#undef TR
#undef TRU
        f16x8 a0 = __builtin_bit_cast(f16x8, u0);
        f16x8 a1 = __builtin_bit_cast(f16x8, u1);
        f16x8 a2 = __builtin_bit_cast(f16x8, u2);
        f16x8 a3 = __builtin_bit_cast(f16x8, u3);
        int rb = m0 + kg * 4;
#define MM2(n) { \
        f32x4 acc = {bias##n, bias##n, bias##n, bias##n}; \
        acc = __builtin_amdgcn_mfma_f32_16x16x32_f16(a0, b##n##_0, acc, 0, 0, 0); \
        acc = __builtin_amdgcn_mfma_f32_16x16x32_f16(a1, b##n##_1, acc, 0, 0, 0); \
        acc = __builtin_amdgcn_mfma_f32_16x16x32_f16(a2, b##n##_2, acc, 0, 0, 0); \
        acc = __builtin_amdgcn_mfma_f32_16x16x32_f16(a3, b##n##_3, acc, 0, 0, 0); \
        y16[(size_t)(rb + 0) * 64 + (n) * 16 + cl] = (_Float16)acc[0]; \
        y16[(size_t)(rb + 1) * 64 + (n) * 16 + cl] = (_Float16)acc[1]; \
        y16[(size_t)(rb + 2) * 64 + (n) * 16 + cl] = (_Float16)acc[2]; \
        y16[(size_t)(rb + 3) * 64 + (n) * 16 + cl] = (_Float16)acc[3]; \
        sum##n += (acc[0] + acc[1]) + (acc[2] + acc[3]); \
        sq##n  += (acc[0]*acc[0] + acc[1]*acc[1]) + (acc[2]*acc[2] + acc[3]*acc[3]); }
        MM2(0) MM2(1) MM2(2) MM2(3)
#undef MM2
    }
#define RD2(n) { \
        float s_ = sum##n, q_ = sq##n; \
        s_ += __shfl_xor(s_, 16); s_ += __shfl_xor(s_, 32); \
        q_ += __shfl_xor(q_, 16); q_ += __shfl_xor(q_, 32); \
        if (l < 16) { red[w][(n) * 16 + l] = s_; red[w][64 + (n) * 16 + l] = q_; } }
    RD2(0) RD2(1) RD2(2) RD2(3)
#undef RD2
    __syncthreads();
    if (tid < 128) {
        float v = red[0][tid] + red[1][tid] + red[2][tid] + red[3][tid];
        atomicAdd(&s2[tid], v);       // one atomic per channel per block
    }
}

// -------------------- final outer BN (no relu): fp16 y -> fp32 out --------------------
__global__ __launch_bounds__(256) void k_bn2(const _Float16* __restrict__ y16,
                                             const float* __restrict__ s2,
                                             const float* __restrict__ g,
                                             const float* __restrict__ b,
                                             float* __restrict__ xout) {
    int idx = blockIdx.x * blockDim.x + threadIdx.x;   // N*8 groups of 8 ch
    if (idx >= N_NODES * 8) return;
    int c0 = (idx & 7) * 8;
    uint4 yin = ((const uint4*)y16)[idx];
    const unsigned* yp = &yin.x;
    float out[8];
#pragma unroll
    for (int q = 0; q < 4; ++q) {
        __half2 hv = __builtin_bit_cast(__half2, yp[q]);
        float v0 = __low2float(hv), v1 = __high2float(hv);
        int c = c0 + 2 * q;
        float mu0 = s2[c] * (1.f / N_NODES);
        float va0 = s2[64 + c] * (1.f / N_NODES) - mu0 * mu0;
        out[2 * q]     = (v0 - mu0) * rsqrtf(va0 + 1e-5f) * g[c] + b[c];
        float mu1 = s2[c + 1] * (1.f / N_NODES);
        float va1 = s2[64 + c + 1] * (1.f / N_NODES) - mu1 * mu1;
        out[2 * q + 1] = (v1 - mu1) * rsqrtf(va1 + 1e-5f) * g[c + 1] + b[c + 1];
    }
    float4* op = (float4*)(xout + (size_t)idx * 8);
    op[0] = make_float4(out[0], out[1], out[2], out[3]);
    op[1] = make_float4(out[4], out[5], out[6], out[7]);
}

extern "C" void kernel_launch(void* const* d_in, const int* in_sizes, int n_in,
                              void* d_out, int out_size, void* d_ws, size_t ws_size,
                              hipStream_t stream) {
    const float* z     = (const float*)d_in[0];
    const int*   batch = (const int*)  d_in[1];
    const int*   eidx  = (const int*)  d_in[2];
    const float* eattr = (const float*)d_in[3];
    const float* lin_w = (const float*)d_in[4];
    const float* lin_b = (const float*)d_in[5];
    const int* src = eidx;
    const int* dst = eidx + N_EDGES;

    char* ws = (char*)d_ws;
    size_t off = 0;
    auto alloc = [&](size_t bytes) -> void* {
        void* p = ws + off;
        off = (off + bytes + 255) & ~(size_t)255;
        return p;
    };
    float*    p        = (float*)   alloc((size_t)B_GRAPH * HID * 4);
    _Float16* bufA     = (_Float16*)alloc((size_t)N_NODES * 64 * 2);
    _Float16* bufB     = (_Float16*)alloc((size_t)N_NODES * 64 * 2);
    _Float16* agg16    = (_Float16*)alloc((size_t)N_NODES * 64 * 2);
    _Float16* t16      = (_Float16*)alloc((size_t)N_NODES * 128 * 2);
    _Float16* wtbuf    = (_Float16*)alloc((size_t)3 * 16384 * 2);
    int*      rowstart = (int*)     alloc((size_t)(N_NODES + 1) * 4);
    int*      cursor   = (int*)     alloc((size_t)(N_NODES + 1) * 4);  // doubles as counts
    int*      btot     = (int*)     alloc(64 * 4);
    int*      boff     = (int*)     alloc(65 * 4);
    int*      csr_src  = (int*)     alloc((size_t)N_EDGES * 4);
    __half2*  attr_h   = (__half2*) alloc((size_t)N_EDGES * 16 * 2);
    float*    stats    = (float*)   alloc((size_t)3 * 512 * 4);

    hipMemsetAsync(cursor, 0, (size_t)(N_NODES + 1) * 4, stream);

    k_setup<<<(N_EDGES + 255) / 256, 256, 0, stream>>>(
        dst, cursor, z, lin_w, lin_b, p,
        (const float*)d_in[6 + 0 * 10 + 2], (const float*)d_in[6 + 0 * 10 + 6],
        (const float*)d_in[6 + 1 * 10 + 2], (const float*)d_in[6 + 1 * 10 + 6],
        (const float*)d_in[6 + 2 * 10 + 2], (const float*)d_in[6 + 2 * 10 + 6],
        wtbuf, stats);
    k_scanA<<<NBLK_SCAN, 1024, 0, stream>>>(cursor, rowstart, btot);
    k_scanB<<<1, 64, 0, stream>>>(btot, boff);
    k_scanC<<<(N_NODES + 256) / 256, 256, 0, stream>>>(rowstart, boff, cursor);
    k_scatgath<<<(N_EDGES + 255) / 256, 256, 0, stream>>>(src, dst, eattr, cursor,
                                                          csr_src, attr_h, p, batch, bufA);

    const _Float16* IN[3]  = { bufA, bufB, bufA };
    _Float16*       OUT[3] = { bufB, bufA, bufB };
    for (int l = 0; l < 3; ++l) {
        const float* ew  = (const float*)d_in[6 + l * 10 + 0];
        const float* eb  = (const float*)d_in[6 + l * 10 + 1];
        const float* b1  = (const float*)d_in[6 + l * 10 + 3];
        const float* bng = (const float*)d_in[6 + l * 10 + 4];
        const float* bnb = (const float*)d_in[6 + l * 10 + 5];
        const float* b2  = (const float*)d_in[6 + l * 10 + 7];
        const _Float16* w1t = wtbuf + l * 16384;
        const _Float16* w2t = wtbuf + l * 16384 + 8192;
        float* s1 = stats + l * 512;          // [0:128] sum t, [128:256] sumsq t
        float* s2 = s1 + 256;                 // [0:64]  sum y, [64:128]  sumsq y
        const float* prev_s2 = (l == 0) ? nullptr : stats + (l - 1) * 512 + 256;
        const float* prev_g  = (l == 0) ? nullptr : (const float*)d_in[6 + (l - 1) * 10 + 8];
        const float* prev_b  = (l == 0) ? nullptr : (const float*)d_in[6 + (l - 1) * 10 + 9];
        float relu_neg = (l == 0) ? -1e30f : 0.f;

        k_edge<<<2048, 256, 0, stream>>>(IN[l], prev_s2, prev_g, prev_b, relu_neg,
                                         rowstart, csr_src, (const _Float16*)attr_h,
                                         ew, eb, agg16);
        k_mlp1<<<128, 256, 0, stream>>>(agg16, w1t, b1, t16, s1);
        k_mlp2<<<128, 256, 0, stream>>>(t16, w2t, b2, s1, bng, bnb, OUT[l], s2);
    }
    k_bn2<<<(N_NODES * 8 + 255) / 256, 256, 0, stream>>>(bufB, stats + 2 * 512 + 256,
                                                         (const float*)d_in[6 + 2 * 10 + 8],
                                                         (const float*)d_in[6 + 2 * 10 + 9],
                                                         (float*)d_out);
}

// Round 15
// 347.773 us; speedup vs baseline: 2.2863x; 1.0004x over previous
//
#include <hip/hip_runtime.h>
#include <hip/hip_fp16.h>

#define N_NODES 50000
#define N_EDGES 800000
#define B_GRAPH 256
#define IN_DIM  128
#define HID     64
#define NBLK_SCAN ((N_NODES + 1023) / 1024)   // 49

typedef _Float16 f16x8 __attribute__((ext_vector_type(8)));
typedef _Float16 f16x2 __attribute__((ext_vector_type(2)));
typedef float    f32x4 __attribute__((ext_vector_type(4)));

// ---------- fused setup: histogram + z-latent + weight transposes + stats zero ----------
__global__ __launch_bounds__(256) void k_setup(const int* __restrict__ dst,
                                               int* __restrict__ counts,
                                               const float* __restrict__ z,
                                               const float* __restrict__ lw,
                                               const float* __restrict__ lb,
                                               float* __restrict__ p,
                                               const float* __restrict__ w1a,
                                               const float* __restrict__ w2a,
                                               const float* __restrict__ w1b,
                                               const float* __restrict__ w2b,
                                               const float* __restrict__ w1c,
                                               const float* __restrict__ w2c,
                                               _Float16* __restrict__ wtbuf,
                                               float* __restrict__ stats) {
    int idx = blockIdx.x * blockDim.x + threadIdx.x;   // grid covers N_EDGES
    if (idx < N_EDGES) atomicAdd(&counts[dst[idx]], 1);
    if (idx < 3 * 512) stats[idx] = 0.f;
    if (idx < 3 * 16384) {                              // weight transpose, 3 layers
        int l = idx >> 14, r = idx & 16383;
        const float* w1 = (l == 0) ? w1a : ((l == 1) ? w1b : w1c);
        const float* w2 = (l == 0) ? w2a : ((l == 1) ? w2b : w2c);
        _Float16* o = wtbuf + l * 16384;
        if (r < 8192) { int k = r >> 7, c = r & 127; o[c * 64 + k] = (_Float16)w1[r]; }
        else { int q = r - 8192; int k = q >> 6, c = q & 63; o[8192 + c * 128 + k] = (_Float16)w2[q]; }
    }
    if (idx < B_GRAPH * HID) {                          // p = relu(z @ lin_w + lin_b)
        int row = idx >> 6, c = idx & 63;
        float acc = lb[c];
        const float* zr = z + row * IN_DIM;
#pragma unroll 8
        for (int k = 0; k < IN_DIM; ++k) acc = fmaf(zr[k], lw[k * HID + c], acc);
        p[idx] = fmaxf(acc, 0.f);
    }
}

// -------------------- CSR scan (two-level) --------------------
__global__ __launch_bounds__(1024) void k_scanA(const int* __restrict__ counts,
                                                int* __restrict__ rowstart,
                                                int* __restrict__ btot) {
    __shared__ int wsum[16];
    int tid = threadIdx.x, lane = tid & 63, w = tid >> 6;
    int i = blockIdx.x * 1024 + tid;
    int v = (i < N_NODES) ? counts[i] : 0;
    int s = v;
#pragma unroll
    for (int off = 1; off < 64; off <<= 1) {
        int t = __shfl_up(s, off, 64);
        if (lane >= off) s += t;
    }
    if (lane == 63) wsum[w] = s;
    __syncthreads();
    if (w == 0) {
        int ws = (lane < 16) ? wsum[lane] : 0;
#pragma unroll
        for (int off = 1; off < 16; off <<= 1) {
            int t = __shfl_up(ws, off, 64);
            if (lane >= off) ws += t;
        }
        if (lane < 16) wsum[lane] = ws;
    }
    __syncthreads();
    int wbase = (w == 0) ? 0 : wsum[w - 1];
    if (i < N_NODES) rowstart[i] = wbase + s - v;
    if (tid == 0) btot[blockIdx.x] = wsum[15];
}

__global__ __launch_bounds__(64) void k_scanB(const int* __restrict__ btot,
                                              int* __restrict__ boff) {
    int lane = threadIdx.x;
    int v = (lane < NBLK_SCAN) ? btot[lane] : 0;
    int s = v;
#pragma unroll
    for (int off = 1; off < 64; off <<= 1) {
        int t = __shfl_up(s, off, 64);
        if (lane >= off) s += t;
    }
    if (lane < NBLK_SCAN) boff[lane] = s - v;
    if (lane == 63) boff[NBLK_SCAN] = s;
}

__global__ __launch_bounds__(256) void k_scanC(int* __restrict__ rowstart,
                                               const int* __restrict__ boff,
                                               int* __restrict__ cursor) {
    int i = blockIdx.x * blockDim.x + threadIdx.x;
    if (i < N_NODES) {
        int r = rowstart[i] + boff[i >> 10];
        rowstart[i] = r;
        cursor[i] = r;
    } else if (i == N_NODES) {
        rowstart[N_NODES] = boff[NBLK_SCAN];
    }
}

// ---------- fused: CSR scatter + packed fp16 attr + latent gather ----------
__global__ __launch_bounds__(256) void k_scatgath(const int* __restrict__ src,
                                                  const int* __restrict__ dst,
                                                  const float* __restrict__ ea,
                                                  int* __restrict__ cursor,
                                                  int* __restrict__ csr_src,
                                                  __half2* __restrict__ attr_h,
                                                  const float* __restrict__ p,
                                                  const int* __restrict__ batch,
                                                  _Float16* __restrict__ x0h) {
    int idx = blockIdx.x * blockDim.x + threadIdx.x;
    if (idx < N_EDGES) {
        int d = dst[idx];
        int pos = atomicAdd(&cursor[d], 1);
        csr_src[pos] = src[idx];
        const float4* s0 = (const float4*)(ea + (size_t)idx * 16);
        float4 f0 = s0[0], f1 = s0[1], f2 = s0[2], f3 = s0[3];
        uint4 u0, u1;
        u0.x = __builtin_bit_cast(unsigned, __floats2half2_rn(f0.x, f0.y));
        u0.y = __builtin_bit_cast(unsigned, __floats2half2_rn(f0.z, f0.w));
        u0.z = __builtin_bit_cast(unsigned, __floats2half2_rn(f1.x, f1.y));
        u0.w = __builtin_bit_cast(unsigned, __floats2half2_rn(f1.z, f1.w));
        u1.x = __builtin_bit_cast(unsigned, __floats2half2_rn(f2.x, f2.y));
        u1.y = __builtin_bit_cast(unsigned, __floats2half2_rn(f2.z, f2.w));
        u1.z = __builtin_bit_cast(unsigned, __floats2half2_rn(f3.x, f3.y));
        u1.w = __builtin_bit_cast(unsigned, __floats2half2_rn(f3.z, f3.w));
        uint4* op = (uint4*)(attr_h + (size_t)pos * 8);
        op[0] = u0;
        op[1] = u1;
    }
    if (idx < N_NODES * 16) {                           // x0h[n] = fp16(p[batch[n]])
        int n = idx >> 4, q = idx & 15;
        float4 v = ((const float4*)(p + batch[n] * 64))[q];
        uint2 u;
        u.x = __builtin_bit_cast(unsigned, __floats2half2_rn(v.x, v.y));
        u.y = __builtin_bit_cast(unsigned, __floats2half2_rn(v.z, v.w));
        ((uint2*)(x0h + (size_t)n * 64 + q * 4))[0] = u;
    }
}

// ---------- edge pass: one wave per node; peeled main loop (clamp/branch-free) ----------
template <bool HAS_BN>
__global__ __launch_bounds__(256) void k_edge(const _Float16* __restrict__ y,
                                              const float* __restrict__ s2,
                                              const float* __restrict__ bg,
                                              const float* __restrict__ bb,
                                              const int* __restrict__ rowstart,
                                              const int* __restrict__ csr_src,
                                              const _Float16* __restrict__ attr_h,
                                              const float* __restrict__ ew,
                                              const float* __restrict__ eb,
                                              _Float16* __restrict__ agg16) {
    int tid = threadIdx.x, lane = tid & 63;
    f16x2 rw[8];
#pragma unroll
    for (int k = 0; k < 8; ++k) {
        f16x2 t;
        t.x = (_Float16)ew[(2 * k) * 64 + lane];
        t.y = (_Float16)ew[(2 * k + 1) * 64 + lane];
        rw[k] = t;
    }
    float ebl = eb[lane];
    float sA = 1.f, sB = 0.f;
    if (HAS_BN) {
        float mu  = s2[lane] * (1.f / N_NODES);
        float var = s2[64 + lane] * (1.f / N_NODES) - mu * mu;
        sA = rsqrtf(var + 1e-5f) * bg[lane];
        sB = bb[lane] - mu * sA;
    }
    int wave = blockIdx.x * 4 + (tid >> 6);
    int nw = gridDim.x * 4;
    for (int n0 = wave; n0 < N_NODES; n0 += nw) {
        int n = __builtin_amdgcn_readfirstlane(n0);
        int beg = rowstart[n], end = rowstart[n + 1];
        int lim = end - 1;
        float yn = (float)y[(size_t)n * 64 + lane];
        float xr = HAS_BN ? fmaxf(fmaf(yn, sA, sB), 0.f) : yn;
        float num = 0.f, den = 0.f;
        int nfull_end = beg + ((end - beg) & ~7);
        int sv = csr_src[min(beg + (lane & 7), lim)];
        // ---- full 8-edge chunks: no clamps, no predication ----
        for (int i = beg; i < nfull_end; i += 8) {
            int sv_cur = sv;
            if (i + 8 < end) sv = csr_src[min(i + 8 + (lane & 7), lim)];
            float xs[8];
            uint4 ua[8], ub[8];
#pragma unroll
            for (int j = 0; j < 8; ++j) {
                int s = __builtin_amdgcn_readlane(sv_cur, j);
                xs[j] = (float)y[(size_t)s * 64 + lane];
                const uint4* ap = (const uint4*)(attr_h + (size_t)(i + j) * 16);
                ua[j] = ap[0];
                ub[j] = ap[1];
            }
#pragma unroll
            for (int j = 0; j < 8; ++j) {
                float el = ebl;
                el = __builtin_amdgcn_fdot2(__builtin_bit_cast(f16x2, ua[j].x), rw[0], el, false);
                el = __builtin_amdgcn_fdot2(__builtin_bit_cast(f16x2, ua[j].y), rw[1], el, false);
                el = __builtin_amdgcn_fdot2(__builtin_bit_cast(f16x2, ua[j].z), rw[2], el, false);
                el = __builtin_amdgcn_fdot2(__builtin_bit_cast(f16x2, ua[j].w), rw[3], el, false);
                el = __builtin_amdgcn_fdot2(__builtin_bit_cast(f16x2, ub[j].x), rw[4], el, false);
                el = __builtin_amdgcn_fdot2(__builtin_bit_cast(f16x2, ub[j].y), rw[5], el, false);
                el = __builtin_amdgcn_fdot2(__builtin_bit_cast(f16x2, ub[j].z), rw[6], el, false);
                el = __builtin_amdgcn_fdot2(__builtin_bit_cast(f16x2, ub[j].w), rw[7], el, false);
                float xv = HAS_BN ? fmaxf(fmaf(xs[j], sA, sB), 0.f) : xs[j];
                float m  = fmaxf(xv + el, 0.f) + 1e-7f;
                float e2 = __expf(m);
                num = fmaf(m, e2, num);
                den += e2;
            }
        }
        // ---- tail chunk (clamped, predicated) ----
        int ns = end - nfull_end;
        if (ns > 0) {
            int i = nfull_end;
            int sv_cur = sv;
            float xs[8];
            uint4 ua[8], ub[8];
#pragma unroll
            for (int j = 0; j < 8; ++j) {
                int s = __builtin_amdgcn_readlane(sv_cur, j);
                xs[j] = (float)y[(size_t)s * 64 + lane];
                int ej = min(i + j, lim);
                const uint4* ap = (const uint4*)(attr_h + (size_t)ej * 16);
                ua[j] = ap[0];
                ub[j] = ap[1];
            }
#pragma unroll
            for (int j = 0; j < 8; ++j) {
                if (j < ns) {
                    float el = ebl;
                    el = __builtin_amdgcn_fdot2(__builtin_bit_cast(f16x2, ua[j].x), rw[0], el, false);
                    el = __builtin_amdgcn_fdot2(__builtin_bit_cast(f16x2, ua[j].y), rw[1], el, false);
                    el = __builtin_amdgcn_fdot2(__builtin_bit_cast(f16x2, ua[j].z), rw[2], el, false);
                    el = __builtin_amdgcn_fdot2(__builtin_bit_cast(f16x2, ua[j].w), rw[3], el, false);
                    el = __builtin_amdgcn_fdot2(__builtin_bit_cast(f16x2, ub[j].x), rw[4], el, false);
                    el = __builtin_amdgcn_fdot2(__builtin_bit_cast(f16x2, ub[j].y), rw[5], el, false);
                    el = __builtin_amdgcn_fdot2(__builtin_bit_cast(f16x2, ub[j].z), rw[6], el, false);
                    el = __builtin_amdgcn_fdot2(__builtin_bit_cast(f16x2, ub[j].w), rw[7], el, false);
                    float xv = HAS_BN ? fmaxf(fmaf(xs[j], sA, sB), 0.f) : xs[j];
                    float m  = fmaxf(xv + el, 0.f) + 1e-7f;
                    float e2 = __expf(m);
                    num = fmaf(m, e2, num);
                    den += e2;
                }
            }
        }
        agg16[(size_t)n * 64 + lane] = (_Float16)(num / (den + 1e-16f) + xr);
    }
}

// -------------------- MFMA mlp1: t16 = agg16 @ w1 + b1 ; block-reduced stats ------------
__global__ __launch_bounds__(256) void k_mlp1(const _Float16* __restrict__ agg16,
                                              const _Float16* __restrict__ w1t,
                                              const float* __restrict__ b1,
                                              _Float16* __restrict__ t16,
                                              float* __restrict__ s1) {
    __shared__ float red[4][256];
    int tid = threadIdx.x, l = tid & 63, w = tid >> 6;
    int cl = l & 15, kg = l >> 4;
#define DB1(n) \
    f16x8 b##n##_0 = *(const f16x8*)&w1t[((n) * 16 + cl) * 64 + kg * 8]; \
    f16x8 b##n##_1 = *(const f16x8*)&w1t[((n) * 16 + cl) * 64 + 32 + kg * 8]; \
    float bias##n = b1[(n) * 16 + cl]; float sum##n = 0.f, sq##n = 0.f;
    DB1(0) DB1(1) DB1(2) DB1(3) DB1(4) DB1(5) DB1(6) DB1(7)
#undef DB1
    int wid = blockIdx.x * 4 + w;
    for (int t = wid; t < N_NODES / 16; t += gridDim.x * 4) {
        int m0 = t * 16;
        const uint4* ap = (const uint4*)(agg16 + (size_t)(m0 + cl) * 64 + kg * 8);
        f16x8 a0 = __builtin_bit_cast(f16x8, ap[0]);
        f16x8 a1 = __builtin_bit_cast(f16x8, ap[4]);
        int rb = m0 + kg * 4;
#define MM1(n) { \
        f32x4 acc = {bias##n, bias##n, bias##n, bias##n}; \
        acc = __builtin_amdgcn_mfma_f32_16x16x32_f16(a0, b##n##_0, acc, 0, 0, 0); \
        acc = __builtin_amdgcn_mfma_f32_16x16x32_f16(a1, b##n##_1, acc, 0, 0, 0); \
        t16[(size_t)(rb + 0) * 128 + (n) * 16 + cl] = (_Float16)acc[0]; \
        t16[(size_t)(rb + 1) * 128 + (n) * 16 + cl] = (_Float16)acc[1]; \
        t16[(size_t)(rb + 2) * 128 + (n) * 16 + cl] = (_Float16)acc[2]; \
        t16[(size_t)(rb + 3) * 128 + (n) * 16 + cl] = (_Float16)acc[3]; \
        sum##n += (acc[0] + acc[1]) + (acc[2] + acc[3]); \
        sq##n  += (acc[0]*acc[0] + acc[1]*acc[1]) + (acc[2]*acc[2] + acc[3]*acc[3]); }
        MM1(0) MM1(1) MM1(2) MM1(3) MM1(4) MM1(5) MM1(6) MM1(7)
#undef MM1
    }
#define RD1(n) { \
        float s_ = sum##n, q_ = sq##n; \
        s_ += __shfl_xor(s_, 16); s_ += __shfl_xor(s_, 32); \
        q_ += __shfl_xor(q_, 16); q_ += __shfl_xor(q_, 32); \
        if (l < 16) { red[w][(n) * 16 + l] = s_; red[w][128 + (n) * 16 + l] = q_; } }
    RD1(0) RD1(1) RD1(2) RD1(3) RD1(4) RD1(5) RD1(6) RD1(7)
#undef RD1
    __syncthreads();
    if (tid < 256) {
        float v = red[0][tid] + red[1][tid] + red[2][tid] + red[3][tid];
        atomicAdd(&s1[tid], v);       // one atomic per channel per block
    }
}

// -------------------- MFMA mlp2 + fused fp32 BN+ReLU ; block-reduced stats -------------
__global__ __launch_bounds__(256) void k_mlp2(const _Float16* __restrict__ t16,
                                              const _Float16* __restrict__ w2t,
                                              const float* __restrict__ b2,
                                              const float* __restrict__ s1,
                                              const float* __restrict__ bng,
                                              const float* __restrict__ bnb,
                                              _Float16* __restrict__ y16,
                                              float* __restrict__ s2) {
    __shared__ float red[4][128];
    int tid = threadIdx.x, l = tid & 63, w = tid >> 6;
    int cl = l & 15, kg = l >> 4;
#define CO32(f) \
    float ca##f[8], cb##f[8]; \
    _Pragma("unroll") \
    for (int e = 0; e < 8; ++e) { \
        int k0 = (f) * 32 + kg * 8 + e; \
        float mu = s1[k0] * (1.f / N_NODES); \
        float va = s1[128 + k0] * (1.f / N_NODES) - mu * mu; \
        float a  = rsqrtf(va + 1e-5f) * bng[k0]; \
        ca##f[e] = a; \
        cb##f[e] = bnb[k0] - mu * a; }
    CO32(0) CO32(1) CO32(2) CO32(3)
#undef CO32
#define DB2(n) \
    f16x8 b##n##_0 = *(const f16x8*)&w2t[((n) * 16 + cl) * 128 +  0 + kg * 8]; \
    f16x8 b##n##_1 = *(const f16x8*)&w2t[((n) * 16 + cl) * 128 + 32 + kg * 8]; \
    f16x8 b##n##_2 = *(const f16x8*)&w2t[((n) * 16 + cl) * 128 + 64 + kg * 8]; \
    f16x8 b##n##_3 = *(const f16x8*)&w2t[((n) * 16 + cl) * 128 + 96 + kg * 8]; \
    float bias##n = b2[(n) * 16 + cl]; float sum##n = 0.f, sq##n = 0.f;
    DB2(0) DB2(1) DB2(2) DB2(3)
#undef DB2
    int wid = blockIdx.x * 4 + w;
    for (int t = wid; t < N_NODES / 16; t += gridDim.x * 4) {
        int m0 = t * 16;
        const uint4* ap = (const uint4*)(t16 + (size_t)(m0 + cl) * 128 + kg * 8);
        uint4 u0 = ap[0], u1 = ap[4], u2 = ap[8], u3 = ap[12];
#define TRU(u, f, q) { \
        __half2 hv = __builtin_bit_cast(__half2, u); \
        float v0 = fmaxf(fmaf(__low2float(hv),  ca##f[2*(q)],     cb##f[2*(q)]),     0.f); \
        float v1 = fmaxf(fmaf(__high2float(hv), ca##f[2*(q) + 1], cb##f[2*(q) + 1]), 0.f); \
        u = __builtin_bit_cast(unsigned, __floats2half2_rn(v0, v1)); }
#define TR(U, f) TRU(U.x, f, 0) TRU(U.y, f, 1) TRU(U.z, f, 2) TRU(U.w, f, 3)
        TR(u0, 0) TR(u1, 1) TR(u2, 2) TR(u3, 3)
#undef TR
#undef TRU
        f16x8 a0 = __builtin_bit_cast(f16x8, u0);
        f16x8 a1 = __builtin_bit_cast(f16x8, u1);
        f16x8 a2 = __builtin_bit_cast(f16x8, u2);
        f16x8 a3 = __builtin_bit_cast(f16x8, u3);
        int rb = m0 + kg * 4;
#define MM2(n) { \
        f32x4 acc = {bias##n, bias##n, bias##n, bias##n}; \
        acc = __builtin_amdgcn_mfma_f32_16x16x32_f16(a0, b##n##_0, acc, 0, 0, 0); \
        acc = __builtin_amdgcn_mfma_f32_16x16x32_f16(a1, b##n##_1, acc, 0, 0, 0); \
        acc = __builtin_amdgcn_mfma_f32_16x16x32_f16(a2, b##n##_2, acc, 0, 0, 0); \
        acc = __builtin_amdgcn_mfma_f32_16x16x32_f16(a3, b##n##_3, acc, 0, 0, 0); \
        y16[(size_t)(rb + 0) * 64 + (n) * 16 + cl] = (_Float16)acc[0]; \
        y16[(size_t)(rb + 1) * 64 + (n) * 16 + cl] = (_Float16)acc[1]; \
        y16[(size_t)(rb + 2) * 64 + (n) * 16 + cl] = (_Float16)acc[2]; \
        y16[(size_t)(rb + 3) * 64 + (n) * 16 + cl] = (_Float16)acc[3]; \
        sum##n += (acc[0] + acc[1]) + (acc[2] + acc[3]); \
        sq##n  += (acc[0]*acc[0] + acc[1]*acc[1]) + (acc[2]*acc[2] + acc[3]*acc[3]); }
        MM2(0) MM2(1) MM2(2) MM2(3)
#undef MM2
    }
#define RD2(n) { \
        float s_ = sum##n, q_ = sq##n; \
        s_ += __shfl_xor(s_, 16); s_ += __shfl_xor(s_, 32); \
        q_ += __shfl_xor(q_, 16); q_ += __shfl_xor(q_, 32); \
        if (l < 16) { red[w][(n) * 16 + l] = s_; red[w][64 + (n) * 16 + l] = q_; } }
    RD2(0) RD2(1) RD2(2) RD2(3)
#undef RD2
    __syncthreads();
    if (tid < 128) {
        float v = red[0][tid] + red[1][tid] + red[2][tid] + red[3][tid];
        atomicAdd(&s2[tid], v);       // one atomic per channel per block
    }
}

// -------------------- final outer BN (no relu): fp16 y -> fp32 out --------------------
__global__ __launch_bounds__(256) void k_bn2(const _Float16* __restrict__ y16,
                                             const float* __restrict__ s2,
                                             const float* __restrict__ g,
                                             const float* __restrict__ b,
                                             float* __restrict__ xout) {
    int idx = blockIdx.x * blockDim.x + threadIdx.x;   // N*8 groups of 8 ch
    if (idx >= N_NODES * 8) return;
    int c0 = (idx & 7) * 8;
    uint4 yin = ((const uint4*)y16)[idx];
    const unsigned* yp = &yin.x;
    float out[8];
#pragma unroll
    for (int q = 0; q < 4; ++q) {
        __half2 hv = __builtin_bit_cast(__half2, yp[q]);
        float v0 = __low2float(hv), v1 = __high2float(hv);
        int c = c0 + 2 * q;
        float mu0 = s2[c] * (1.f / N_NODES);
        float va0 = s2[64 + c] * (1.f / N_NODES) - mu0 * mu0;
        out[2 * q]     = (v0 - mu0) * rsqrtf(va0 + 1e-5f) * g[c] + b[c];
        float mu1 = s2[c + 1] * (1.f / N_NODES);
        float va1 = s2[64 + c + 1] * (1.f / N_NODES) - mu1 * mu1;
        out[2 * q + 1] = (v1 - mu1) * rsqrtf(va1 + 1e-5f) * g[c + 1] + b[c + 1];
    }
    float4* op = (float4*)(xout + (size_t)idx * 8);
    op[0] = make_float4(out[0], out[1], out[2], out[3]);
    op[1] = make_float4(out[4], out[5], out[6], out[7]);
}

extern "C" void kernel_launch(void* const* d_in, const int* in_sizes, int n_in,
                              void* d_out, int out_size, void* d_ws, size_t ws_size,
                              hipStream_t stream) {
    const float* z     = (const float*)d_in[0];
    const int*   batch = (const int*)  d_in[1];
    const int*   eidx  = (const int*)  d_in[2];
    const float* eattr = (const float*)d_in[3];
    const float* lin_w = (const float*)d_in[4];
    const float* lin_b = (const float*)d_in[5];
    const int* src = eidx;
    const int* dst = eidx + N_EDGES;

    char* ws = (char*)d_ws;
    size_t off = 0;
    auto alloc = [&](size_t bytes) -> void* {
        void* p = ws + off;
        off = (off + bytes + 255) & ~(size_t)255;
        return p;
    };
    float*    p        = (float*)   alloc((size_t)B_GRAPH * HID * 4);
    _Float16* bufA     = (_Float16*)alloc((size_t)N_NODES * 64 * 2);
    _Float16* bufB     = (_Float16*)alloc((size_t)N_NODES * 64 * 2);
    _Float16* agg16    = (_Float16*)alloc((size_t)N_NODES * 64 * 2);
    _Float16* t16      = (_Float16*)alloc((size_t)N_NODES * 128 * 2);
    _Float16* wtbuf    = (_Float16*)alloc((size_t)3 * 16384 * 2);
    int*      rowstart = (int*)     alloc((size_t)(N_NODES + 1) * 4);
    int*      cursor   = (int*)     alloc((size_t)(N_NODES + 1) * 4);  // doubles as counts
    int*      btot     = (int*)     alloc(64 * 4);
    int*      boff     = (int*)     alloc(65 * 4);
    int*      csr_src  = (int*)     alloc((size_t)N_EDGES * 4);
    __half2*  attr_h   = (__half2*) alloc((size_t)N_EDGES * 16 * 2);
    float*    stats    = (float*)   alloc((size_t)3 * 512 * 4);

    hipMemsetAsync(cursor, 0, (size_t)(N_NODES + 1) * 4, stream);

    k_setup<<<(N_EDGES + 255) / 256, 256, 0, stream>>>(
        dst, cursor, z, lin_w, lin_b, p,
        (const float*)d_in[6 + 0 * 10 + 2], (const float*)d_in[6 + 0 * 10 + 6],
        (const float*)d_in[6 + 1 * 10 + 2], (const float*)d_in[6 + 1 * 10 + 6],
        (const float*)d_in[6 + 2 * 10 + 2], (const float*)d_in[6 + 2 * 10 + 6],
        wtbuf, stats);
    k_scanA<<<NBLK_SCAN, 1024, 0, stream>>>(cursor, rowstart, btot);
    k_scanB<<<1, 64, 0, stream>>>(btot, boff);
    k_scanC<<<(N_NODES + 256) / 256, 256, 0, stream>>>(rowstart, boff, cursor);
    k_scatgath<<<(N_EDGES + 255) / 256, 256, 0, stream>>>(src, dst, eattr, cursor,
                                                          csr_src, attr_h, p, batch, bufA);

    const _Float16* IN[3]  = { bufA, bufB, bufA };
    _Float16*       OUT[3] = { bufB, bufA, bufB };
    for (int l = 0; l < 3; ++l) {
        const float* ew  = (const float*)d_in[6 + l * 10 + 0];
        const float* eb  = (const float*)d_in[6 + l * 10 + 1];
        const float* b1  = (const float*)d_in[6 + l * 10 + 3];
        const float* bng = (const float*)d_in[6 + l * 10 + 4];
        const float* bnb = (const float*)d_in[6 + l * 10 + 5];
        const float* b2  = (const float*)d_in[6 + l * 10 + 7];
        const _Float16* w1t = wtbuf + l * 16384;
        const _Float16* w2t = wtbuf + l * 16384 + 8192;
        float* s1 = stats + l * 512;          // [0:128] sum t, [128:256] sumsq t
        float* s2 = s1 + 256;                 // [0:64]  sum y, [64:128]  sumsq y
        const float* prev_s2 = (l == 0) ? nullptr : stats + (l - 1) * 512 + 256;
        const float* prev_g  = (l == 0) ? nullptr : (const float*)d_in[6 + (l - 1) * 10 + 8];
        const float* prev_b  = (l == 0) ? nullptr : (const float*)d_in[6 + (l - 1) * 10 + 9];

        if (l == 0)
            k_edge<false><<<2048, 256, 0, stream>>>(IN[l], nullptr, nullptr, nullptr,
                                                    rowstart, csr_src, (const _Float16*)attr_h,
                                                    ew, eb, agg16);
        else
            k_edge<true><<<2048, 256, 0, stream>>>(IN[l], prev_s2, prev_g, prev_b,
                                                   rowstart, csr_src, (const _Float16*)attr_h,
                                                   ew, eb, agg16);
        k_mlp1<<<128, 256, 0, stream>>>(agg16, w1t, b1, t16, s1);
        k_mlp2<<<128, 256, 0, stream>>>(t16, w2t, b2, s1, bng, bnb, OUT[l], s2);
    }
    k_bn2<<<(N_NODES * 8 + 255) / 256, 256, 0, stream>>>(bufB, stats + 2 * 512 + 256,
                                                         (const float*)d_in[6 + 2 * 10 + 8],
                                                         (const float*)d_in[6 + 2 * 10 + 9],
                                                         (float*)d_out);
}

// Round 16
// 338.128 us; speedup vs baseline: 2.3515x; 1.0285x over previous
//
#include <hip/hip_runtime.h>
#include <hip/hip_fp16.h>

#define N_NODES 50000
#define N_EDGES 800000
#define B_GRAPH 256
#define IN_DIM  128
#define HID     64
#define NBLK_SCAN ((N_NODES + 1023) / 1024)   // 49

typedef _Float16 f16x8 __attribute__((ext_vector_type(8)));
typedef _Float16 f16x2 __attribute__((ext_vector_type(2)));
typedef float    f32x4 __attribute__((ext_vector_type(4)));

// ---------- fused setup: histogram + z-latent + weight transposes + stats zero ----------
__global__ __launch_bounds__(256) void k_setup(const int* __restrict__ dst,
                                               int* __restrict__ counts,
                                               const float* __restrict__ z,
                                               const float* __restrict__ lw,
                                               const float* __restrict__ lb,
                                               float* __restrict__ p,
                                               const float* __restrict__ w1a,
                                               const float* __restrict__ w2a,
                                               const float* __restrict__ w1b,
                                               const float* __restrict__ w2b,
                                               const float* __restrict__ w1c,
                                               const float* __restrict__ w2c,
                                               _Float16* __restrict__ wtbuf,
                                               float* __restrict__ stats) {
    int idx = blockIdx.x * blockDim.x + threadIdx.x;   // grid covers N_EDGES
    if (idx < N_EDGES) atomicAdd(&counts[dst[idx]], 1);
    if (idx < 3 * 512) stats[idx] = 0.f;
    if (idx < 3 * 16384) {                              // weight transpose, 3 layers
        int l = idx >> 14, r = idx & 16383;
        const float* w1 = (l == 0) ? w1a : ((l == 1) ? w1b : w1c);
        const float* w2 = (l == 0) ? w2a : ((l == 1) ? w2b : w2c);
        _Float16* o = wtbuf + l * 16384;
        if (r < 8192) { int k = r >> 7, c = r & 127; o[c * 64 + k] = (_Float16)w1[r]; }
        else { int q = r - 8192; int k = q >> 6, c = q & 63; o[8192 + c * 128 + k] = (_Float16)w2[q]; }
    }
    if (idx < B_GRAPH * HID) {                          // p = relu(z @ lin_w + lin_b)
        int row = idx >> 6, c = idx & 63;
        float acc = lb[c];
        const float* zr = z + row * IN_DIM;
#pragma unroll 8
        for (int k = 0; k < IN_DIM; ++k) acc = fmaf(zr[k], lw[k * HID + c], acc);
        p[idx] = fmaxf(acc, 0.f);
    }
}

// -------------------- CSR scan: per-1024-block local scan + block totals --------------------
__global__ __launch_bounds__(1024) void k_scanA(const int* __restrict__ counts,
                                                int* __restrict__ rowstart,
                                                int* __restrict__ btot) {
    __shared__ int wsum[16];
    int tid = threadIdx.x, lane = tid & 63, w = tid >> 6;
    int i = blockIdx.x * 1024 + tid;
    int v = (i < N_NODES) ? counts[i] : 0;
    int s = v;
#pragma unroll
    for (int off = 1; off < 64; off <<= 1) {
        int t = __shfl_up(s, off, 64);
        if (lane >= off) s += t;
    }
    if (lane == 63) wsum[w] = s;
    __syncthreads();
    if (w == 0) {
        int ws = (lane < 16) ? wsum[lane] : 0;
#pragma unroll
        for (int off = 1; off < 16; off <<= 1) {
            int t = __shfl_up(ws, off, 64);
            if (lane >= off) ws += t;
        }
        if (lane < 16) wsum[lane] = ws;
    }
    __syncthreads();
    int wbase = (w == 0) ? 0 : wsum[w - 1];
    if (i < N_NODES) rowstart[i] = wbase + s - v;
    if (tid == 0) btot[blockIdx.x] = wsum[15];
}

// scanC with fused block-offset scan (replaces old scanB+scanC)
__global__ __launch_bounds__(256) void k_scanC(int* __restrict__ rowstart,
                                               const int* __restrict__ btot,
                                               int* __restrict__ cursor) {
    __shared__ int sboff[64];
    int tid = threadIdx.x;
    if (tid < 64) {
        int v = (tid < NBLK_SCAN) ? btot[tid] : 0;
        int s = v;
#pragma unroll
        for (int off = 1; off < 64; off <<= 1) {
            int t = __shfl_up(s, off, 64);
            if (tid >= off) s += t;
        }
        sboff[tid] = s - v;   // exclusive; sboff[63] == grand total
    }
    __syncthreads();
    int i = blockIdx.x * blockDim.x + tid;
    if (i < N_NODES) {
        int r = rowstart[i] + sboff[i >> 10];
        rowstart[i] = r;
        cursor[i] = r;
    } else if (i == N_NODES) {
        rowstart[N_NODES] = sboff[63];
    }
}

// ---------- fused: CSR scatter + packed fp16 attr + latent gather ----------
__global__ __launch_bounds__(256) void k_scatgath(const int* __restrict__ src,
                                                  const int* __restrict__ dst,
                                                  const float* __restrict__ ea,
                                                  int* __restrict__ cursor,
                                                  int* __restrict__ csr_src,
                                                  __half2* __restrict__ attr_h,
                                                  const float* __restrict__ p,
                                                  const int* __restrict__ batch,
                                                  _Float16* __restrict__ x0h) {
    int idx = blockIdx.x * blockDim.x + threadIdx.x;
    if (idx < N_EDGES) {
        int d = dst[idx];
        int pos = atomicAdd(&cursor[d], 1);
        csr_src[pos] = src[idx];
        const float4* s0 = (const float4*)(ea + (size_t)idx * 16);
        float4 f0 = s0[0], f1 = s0[1], f2 = s0[2], f3 = s0[3];
        uint4 u0, u1;
        u0.x = __builtin_bit_cast(unsigned, __floats2half2_rn(f0.x, f0.y));
        u0.y = __builtin_bit_cast(unsigned, __floats2half2_rn(f0.z, f0.w));
        u0.z = __builtin_bit_cast(unsigned, __floats2half2_rn(f1.x, f1.y));
        u0.w = __builtin_bit_cast(unsigned, __floats2half2_rn(f1.z, f1.w));
        u1.x = __builtin_bit_cast(unsigned, __floats2half2_rn(f2.x, f2.y));
        u1.y = __builtin_bit_cast(unsigned, __floats2half2_rn(f2.z, f2.w));
        u1.z = __builtin_bit_cast(unsigned, __floats2half2_rn(f3.x, f3.y));
        u1.w = __builtin_bit_cast(unsigned, __floats2half2_rn(f3.z, f3.w));
        uint4* op = (uint4*)(attr_h + (size_t)pos * 8);
        op[0] = u0;
        op[1] = u1;
    }
    if (idx < N_NODES * 16) {                           // x0h[n] = fp16(p[batch[n]])
        int n = idx >> 4, q = idx & 15;
        float4 v = ((const float4*)(p + batch[n] * 64))[q];
        uint2 u;
        u.x = __builtin_bit_cast(unsigned, __floats2half2_rn(v.x, v.y));
        u.y = __builtin_bit_cast(unsigned, __floats2half2_rn(v.z, v.w));
        ((uint2*)(x0h + (size_t)n * 64 + q * 4))[0] = u;
    }
}

// ---------- edge pass: one wave per node; peeled main loop (clamp/branch-free) ----------
template <bool HAS_BN>
__global__ __launch_bounds__(256) void k_edge(const _Float16* __restrict__ y,
                                              const float* __restrict__ s2,
                                              const float* __restrict__ bg,
                                              const float* __restrict__ bb,
                                              const int* __restrict__ rowstart,
                                              const int* __restrict__ csr_src,
                                              const _Float16* __restrict__ attr_h,
                                              const float* __restrict__ ew,
                                              const float* __restrict__ eb,
                                              _Float16* __restrict__ agg16) {
    int tid = threadIdx.x, lane = tid & 63;
    f16x2 rw[8];
#pragma unroll
    for (int k = 0; k < 8; ++k) {
        f16x2 t;
        t.x = (_Float16)ew[(2 * k) * 64 + lane];
        t.y = (_Float16)ew[(2 * k + 1) * 64 + lane];
        rw[k] = t;
    }
    float ebl = eb[lane];
    float sA = 1.f, sB = 0.f;
    if (HAS_BN) {
        float mu  = s2[lane] * (1.f / N_NODES);
        float var = s2[64 + lane] * (1.f / N_NODES) - mu * mu;
        sA = rsqrtf(var + 1e-5f) * bg[lane];
        sB = bb[lane] - mu * sA;
    }
    int wave = blockIdx.x * 4 + (tid >> 6);
    int nw = gridDim.x * 4;
    for (int n0 = wave; n0 < N_NODES; n0 += nw) {
        int n = __builtin_amdgcn_readfirstlane(n0);
        int beg = rowstart[n], end = rowstart[n + 1];
        int lim = end - 1;
        float yn = (float)y[(size_t)n * 64 + lane];
        float xr = HAS_BN ? fmaxf(fmaf(yn, sA, sB), 0.f) : yn;
        float num = 0.f, den = 0.f;
        int nfull_end = beg + ((end - beg) & ~7);
        int sv = csr_src[min(beg + (lane & 7), lim)];
        // ---- full 8-edge chunks: no clamps, no predication ----
        for (int i = beg; i < nfull_end; i += 8) {
            int sv_cur = sv;
            if (i + 8 < end) sv = csr_src[min(i + 8 + (lane & 7), lim)];
            float xs[8];
            uint4 ua[8], ub[8];
#pragma unroll
            for (int j = 0; j < 8; ++j) {
                int s = __builtin_amdgcn_readlane(sv_cur, j);
                xs[j] = (float)y[(size_t)s * 64 + lane];
                const uint4* ap = (const uint4*)(attr_h + (size_t)(i + j) * 16);
                ua[j] = ap[0];
                ub[j] = ap[1];
            }
#pragma unroll
            for (int j = 0; j < 8; ++j) {
                float el = ebl;
                el = __builtin_amdgcn_fdot2(__builtin_bit_cast(f16x2, ua[j].x), rw[0], el, false);
                el = __builtin_amdgcn_fdot2(__builtin_bit_cast(f16x2, ua[j].y), rw[1], el, false);
                el = __builtin_amdgcn_fdot2(__builtin_bit_cast(f16x2, ua[j].z), rw[2], el, false);
                el = __builtin_amdgcn_fdot2(__builtin_bit_cast(f16x2, ua[j].w), rw[3], el, false);
                el = __builtin_amdgcn_fdot2(__builtin_bit_cast(f16x2, ub[j].x), rw[4], el, false);
                el = __builtin_amdgcn_fdot2(__builtin_bit_cast(f16x2, ub[j].y), rw[5], el, false);
                el = __builtin_amdgcn_fdot2(__builtin_bit_cast(f16x2, ub[j].z), rw[6], el, false);
                el = __builtin_amdgcn_fdot2(__builtin_bit_cast(f16x2, ub[j].w), rw[7], el, false);
                float xv = HAS_BN ? fmaxf(fmaf(xs[j], sA, sB), 0.f) : xs[j];
                float m  = fmaxf(xv + el, 0.f) + 1e-7f;
                float e2 = __expf(m);
                num = fmaf(m, e2, num);
                den += e2;
            }
        }
        // ---- tail chunk (clamped, predicated) ----
        int ns = end - nfull_end;
        if (ns > 0) {
            int i = nfull_end;
            int sv_cur = sv;
            float xs[8];
            uint4 ua[8], ub[8];
#pragma unroll
            for (int j = 0; j < 8; ++j) {
                int s = __builtin_amdgcn_readlane(sv_cur, j);
                xs[j] = (float)y[(size_t)s * 64 + lane];
                int ej = min(i + j, lim);
                const uint4* ap = (const uint4*)(attr_h + (size_t)ej * 16);
                ua[j] = ap[0];
                ub[j] = ap[1];
            }
#pragma unroll
            for (int j = 0; j < 8; ++j) {
                if (j < ns) {
                    float el = ebl;
                    el = __builtin_amdgcn_fdot2(__builtin_bit_cast(f16x2, ua[j].x), rw[0], el, false);
                    el = __builtin_amdgcn_fdot2(__builtin_bit_cast(f16x2, ua[j].y), rw[1], el, false);
                    el = __builtin_amdgcn_fdot2(__builtin_bit_cast(f16x2, ua[j].z), rw[2], el, false);
                    el = __builtin_amdgcn_fdot2(__builtin_bit_cast(f16x2, ua[j].w), rw[3], el, false);
                    el = __builtin_amdgcn_fdot2(__builtin_bit_cast(f16x2, ub[j].x), rw[4], el, false);
                    el = __builtin_amdgcn_fdot2(__builtin_bit_cast(f16x2, ub[j].y), rw[5], el, false);
                    el = __builtin_amdgcn_fdot2(__builtin_bit_cast(f16x2, ub[j].z), rw[6], el, false);
                    el = __builtin_amdgcn_fdot2(__builtin_bit_cast(f16x2, ub[j].w), rw[7], el, false);
                    float xv = HAS_BN ? fmaxf(fmaf(xs[j], sA, sB), 0.f) : xs[j];
                    float m  = fmaxf(xv + el, 0.f) + 1e-7f;
                    float e2 = __expf(m);
                    num = fmaf(m, e2, num);
                    den += e2;
                }
            }
        }
        agg16[(size_t)n * 64 + lane] = (_Float16)(num / (den + 1e-16f) + xr);
    }
}

// -------------------- MFMA mlp1: t16 = agg16 @ w1 + b1 ; block-reduced stats ------------
__global__ __launch_bounds__(256) void k_mlp1(const _Float16* __restrict__ agg16,
                                              const _Float16* __restrict__ w1t,
                                              const float* __restrict__ b1,
                                              _Float16* __restrict__ t16,
                                              float* __restrict__ s1) {
    __shared__ float red[4][256];
    int tid = threadIdx.x, l = tid & 63, w = tid >> 6;
    int cl = l & 15, kg = l >> 4;
#define DB1(n) \
    f16x8 b##n##_0 = *(const f16x8*)&w1t[((n) * 16 + cl) * 64 + kg * 8]; \
    f16x8 b##n##_1 = *(const f16x8*)&w1t[((n) * 16 + cl) * 64 + 32 + kg * 8]; \
    float bias##n = b1[(n) * 16 + cl]; float sum##n = 0.f, sq##n = 0.f;
    DB1(0) DB1(1) DB1(2) DB1(3) DB1(4) DB1(5) DB1(6) DB1(7)
#undef DB1
    int wid = blockIdx.x * 4 + w;
    for (int t = wid; t < N_NODES / 16; t += gridDim.x * 4) {
        int m0 = t * 16;
        const uint4* ap = (const uint4*)(agg16 + (size_t)(m0 + cl) * 64 + kg * 8);
        f16x8 a0 = __builtin_bit_cast(f16x8, ap[0]);
        f16x8 a1 = __builtin_bit_cast(f16x8, ap[4]);
        int rb = m0 + kg * 4;
#define MM1(n) { \
        f32x4 acc = {bias##n, bias##n, bias##n, bias##n}; \
        acc = __builtin_amdgcn_mfma_f32_16x16x32_f16(a0, b##n##_0, acc, 0, 0, 0); \
        acc = __builtin_amdgcn_mfma_f32_16x16x32_f16(a1, b##n##_1, acc, 0, 0, 0); \
        t16[(size_t)(rb + 0) * 128 + (n) * 16 + cl] = (_Float16)acc[0]; \
        t16[(size_t)(rb + 1) * 128 + (n) * 16 + cl] = (_Float16)acc[1]; \
        t16[(size_t)(rb + 2) * 128 + (n) * 16 + cl] = (_Float16)acc[2]; \
        t16[(size_t)(rb + 3) * 128 + (n) * 16 + cl] = (_Float16)acc[3]; \
        sum##n += (acc[0] + acc[1]) + (acc[2] + acc[3]); \
        sq##n  += (acc[0]*acc[0] + acc[1]*acc[1]) + (acc[2]*acc[2] + acc[3]*acc[3]); }
        MM1(0) MM1(1) MM1(2) MM1(3) MM1(4) MM1(5) MM1(6) MM1(7)
#undef MM1
    }
#define RD1(n) { \
        float s_ = sum##n, q_ = sq##n; \
        s_ += __shfl_xor(s_, 16); s_ += __shfl_xor(s_, 32); \
        q_ += __shfl_xor(q_, 16); q_ += __shfl_xor(q_, 32); \
        if (l < 16) { red[w][(n) * 16 + l] = s_; red[w][128 + (n) * 16 + l] = q_; } }
    RD1(0) RD1(1) RD1(2) RD1(3) RD1(4) RD1(5) RD1(6) RD1(7)
#undef RD1
    __syncthreads();
    if (tid < 256) {
        float v = red[0][tid] + red[1][tid] + red[2][tid] + red[3][tid];
        atomicAdd(&s1[tid], v);       // one atomic per channel per block
    }
}

// -------------------- MFMA mlp2 + fused fp32 BN+ReLU ; block-reduced stats -------------
__global__ __launch_bounds__(256) void k_mlp2(const _Float16* __restrict__ t16,
                                              const _Float16* __restrict__ w2t,
                                              const float* __restrict__ b2,
                                              const float* __restrict__ s1,
                                              const float* __restrict__ bng,
                                              const float* __restrict__ bnb,
                                              _Float16* __restrict__ y16,
                                              float* __restrict__ s2) {
    __shared__ float red[4][128];
    int tid = threadIdx.x, l = tid & 63, w = tid >> 6;
    int cl = l & 15, kg = l >> 4;
#define CO32(f) \
    float ca##f[8], cb##f[8]; \
    _Pragma("unroll") \
    for (int e = 0; e < 8; ++e) { \
        int k0 = (f) * 32 + kg * 8 + e; \
        float mu = s1[k0] * (1.f / N_NODES); \
        float va = s1[128 + k0] * (1.f / N_NODES) - mu * mu; \
        float a  = rsqrtf(va + 1e-5f) * bng[k0]; \
        ca##f[e] = a; \
        cb##f[e] = bnb[k0] - mu * a; }
    CO32(0) CO32(1) CO32(2) CO32(3)
#undef CO32
#define DB2(n) \
    f16x8 b##n##_0 = *(const f16x8*)&w2t[((n) * 16 + cl) * 128 +  0 + kg * 8]; \
    f16x8 b##n##_1 = *(const f16x8*)&w2t[((n) * 16 + cl) * 128 + 32 + kg * 8]; \
    f16x8 b##n##_2 = *(const f16x8*)&w2t[((n) * 16 + cl) * 128 + 64 + kg * 8]; \
    f16x8 b##n##_3 = *(const f16x8*)&w2t[((n) * 16 + cl) * 128 + 96 + kg * 8]; \
    float bias##n = b2[(n) * 16 + cl]; float sum##n = 0.f, sq##n = 0.f;
    DB2(0) DB2(1) DB2(2) DB2(3)
#undef DB2
    int wid = blockIdx.x * 4 + w;
    for (int t = wid; t < N_NODES / 16; t += gridDim.x * 4) {
        int m0 = t * 16;
        const uint4* ap = (const uint4*)(t16 + (size_t)(m0 + cl) * 128 + kg * 8);
        uint4 u0 = ap[0], u1 = ap[4], u2 = ap[8], u3 = ap[12];
#define TRU(u, f, q) { \
        __half2 hv = __builtin_bit_cast(__half2, u); \
        float v0 = fmaxf(fmaf(__low2float(hv),  ca##f[2*(q)],     cb##f[2*(q)]),     0.f); \
        float v1 = fmaxf(fmaf(__high2float(hv), ca##f[2*(q) + 1], cb##f[2*(q) + 1]), 0.f); \
        u = __builtin_bit_cast(unsigned, __floats2half2_rn(v0, v1)); }
#define TR(U, f) TRU(U.x, f, 0) TRU(U.y, f, 1) TRU(U.z, f, 2) TRU(U.w, f, 3)
        TR(u0, 0) TR(u1, 1) TR(u2, 2) TR(u3, 3)
#undef TR
#undef TRU
        f16x8 a0 = __builtin_bit_cast(f16x8, u0);
        f16x8 a1 = __builtin_bit_cast(f16x8, u1);
        f16x8 a2 = __builtin_bit_cast(f16x8, u2);
        f16x8 a3 = __builtin_bit_cast(f16x8, u3);
        int rb = m0 + kg * 4;
#define MM2(n) { \
        f32x4 acc = {bias##n, bias##n, bias##n, bias##n}; \
        acc = __builtin_amdgcn_mfma_f32_16x16x32_f16(a0, b##n##_0, acc, 0, 0, 0); \
        acc = __builtin_amdgcn_mfma_f32_16x16x32_f16(a1, b##n##_1, acc, 0, 0, 0); \
        acc = __builtin_amdgcn_mfma_f32_16x16x32_f16(a2, b##n##_2, acc, 0, 0, 0); \
        acc = __builtin_amdgcn_mfma_f32_16x16x32_f16(a3, b##n##_3, acc, 0, 0, 0); \
        y16[(size_t)(rb + 0) * 64 + (n) * 16 + cl] = (_Float16)acc[0]; \
        y16[(size_t)(rb + 1) * 64 + (n) * 16 + cl] = (_Float16)acc[1]; \
        y16[(size_t)(rb + 2) * 64 + (n) * 16 + cl] = (_Float16)acc[2]; \
        y16[(size_t)(rb + 3) * 64 + (n) * 16 + cl] = (_Float16)acc[3]; \
        sum##n += (acc[0] + acc[1]) + (acc[2] + acc[3]); \
        sq##n  += (acc[0]*acc[0] + acc[1]*acc[1]) + (acc[2]*acc[2] + acc[3]*acc[3]); }
        MM2(0) MM2(1) MM2(2) MM2(3)
#undef MM2
    }
#define RD2(n) { \
        float s_ = sum##n, q_ = sq##n; \
        s_ += __shfl_xor(s_, 16); s_ += __shfl_xor(s_, 32); \
        q_ += __shfl_xor(q_, 16); q_ += __shfl_xor(q_, 32); \
        if (l < 16) { red[w][(n) * 16 + l] = s_; red[w][64 + (n) * 16 + l] = q_; } }
    RD2(0) RD2(1) RD2(2) RD2(3)
#undef RD2
    __syncthreads();
    if (tid < 128) {
        float v = red[0][tid] + red[1][tid] + red[2][tid] + red[3][tid];
        atomicAdd(&s2[tid], v);       // one atomic per channel per block
    }
}

// -------------------- final outer BN (no relu): fp16 y -> fp32 out --------------------
__global__ __launch_bounds__(256) void k_bn2(const _Float16* __restrict__ y16,
                                             const float* __restrict__ s2,
                                             const float* __restrict__ g,
                                             const float* __restrict__ b,
                                             float* __restrict__ xout) {
    int idx = blockIdx.x * blockDim.x + threadIdx.x;   // N*8 groups of 8 ch
    if (idx >= N_NODES * 8) return;
    int c0 = (idx & 7) * 8;
    uint4 yin = ((const uint4*)y16)[idx];
    const unsigned* yp = &yin.x;
    float out[8];
#pragma unroll
    for (int q = 0; q < 4; ++q) {
        __half2 hv = __builtin_bit_cast(__half2, yp[q]);
        float v0 = __low2float(hv), v1 = __high2float(hv);
        int c = c0 + 2 * q;
        float mu0 = s2[c] * (1.f / N_NODES);
        float va0 = s2[64 + c] * (1.f / N_NODES) - mu0 * mu0;
        out[2 * q]     = (v0 - mu0) * rsqrtf(va0 + 1e-5f) * g[c] + b[c];
        float mu1 = s2[c + 1] * (1.f / N_NODES);
        float va1 = s2[64 + c + 1] * (1.f / N_NODES) - mu1 * mu1;
        out[2 * q + 1] = (v1 - mu1) * rsqrtf(va1 + 1e-5f) * g[c + 1] + b[c + 1];
    }
    float4* op = (float4*)(xout + (size_t)idx * 8);
    op[0] = make_float4(out[0], out[1], out[2], out[3]);
    op[1] = make_float4(out[4], out[5], out[6], out[7]);
}

extern "C" void kernel_launch(void* const* d_in, const int* in_sizes, int n_in,
                              void* d_out, int out_size, void* d_ws, size_t ws_size,
                              hipStream_t stream) {
    const float* z     = (const float*)d_in[0];
    const int*   batch = (const int*)  d_in[1];
    const int*   eidx  = (const int*)  d_in[2];
    const float* eattr = (const float*)d_in[3];
    const float* lin_w = (const float*)d_in[4];
    const float* lin_b = (const float*)d_in[5];
    const int* src = eidx;
    const int* dst = eidx + N_EDGES;

    char* ws = (char*)d_ws;
    size_t off = 0;
    auto alloc = [&](size_t bytes) -> void* {
        void* p = ws + off;
        off = (off + bytes + 255) & ~(size_t)255;
        return p;
    };
    float*    p        = (float*)   alloc((size_t)B_GRAPH * HID * 4);
    _Float16* bufA     = (_Float16*)alloc((size_t)N_NODES * 64 * 2);
    _Float16* bufB     = (_Float16*)alloc((size_t)N_NODES * 64 * 2);
    _Float16* agg16    = (_Float16*)alloc((size_t)N_NODES * 64 * 2);
    _Float16* t16      = (_Float16*)alloc((size_t)N_NODES * 128 * 2);
    _Float16* wtbuf    = (_Float16*)alloc((size_t)3 * 16384 * 2);
    int*      rowstart = (int*)     alloc((size_t)(N_NODES + 1) * 4);
    int*      cursor   = (int*)     alloc((size_t)(N_NODES + 1) * 4);  // doubles as counts
    int*      btot     = (int*)     alloc(64 * 4);
    int*      csr_src  = (int*)     alloc((size_t)N_EDGES * 4);
    __half2*  attr_h   = (__half2*) alloc((size_t)N_EDGES * 16 * 2);
    float*    stats    = (float*)   alloc((size_t)3 * 512 * 4);

    hipMemsetAsync(cursor, 0, (size_t)(N_NODES + 1) * 4, stream);

    k_setup<<<(N_EDGES + 255) / 256, 256, 0, stream>>>(
        dst, cursor, z, lin_w, lin_b, p,
        (const float*)d_in[6 + 0 * 10 + 2], (const float*)d_in[6 + 0 * 10 + 6],
        (const float*)d_in[6 + 1 * 10 + 2], (const float*)d_in[6 + 1 * 10 + 6],
        (const float*)d_in[6 + 2 * 10 + 2], (const float*)d_in[6 + 2 * 10 + 6],
        wtbuf, stats);
    k_scanA<<<NBLK_SCAN, 1024, 0, stream>>>(cursor, rowstart, btot);
    k_scanC<<<(N_NODES + 256) / 256, 256, 0, stream>>>(rowstart, btot, cursor);
    k_scatgath<<<(N_EDGES + 255) / 256, 256, 0, stream>>>(src, dst, eattr, cursor,
                                                          csr_src, attr_h, p, batch, bufA);

    const _Float16* IN[3]  = { bufA, bufB, bufA };
    _Float16*       OUT[3] = { bufB, bufA, bufB };
    for (int l = 0; l < 3; ++l) {
        const float* ew  = (const float*)d_in[6 + l * 10 + 0];
        const float* eb  = (const float*)d_in[6 + l * 10 + 1];
        const float* b1  = (const float*)d_in[6 + l * 10 + 3];
        const float* bng = (const float*)d_in[6 + l * 10 + 4];
        const float* bnb = (const float*)d_in[6 + l * 10 + 5];
        const float* b2  = (const float*)d_in[6 + l * 10 + 7];
        const _Float16* w1t = wtbuf + l * 16384;
        const _Float16* w2t = wtbuf + l * 16384 + 8192;
        float* s1 = stats + l * 512;          // [0:128] sum t, [128:256] sumsq t
        float* s2 = s1 + 256;                 // [0:64]  sum y, [64:128]  sumsq y
        const float* prev_s2 = (l == 0) ? nullptr : stats + (l - 1) * 512 + 256;
        const float* prev_g  = (l == 0) ? nullptr : (const float*)d_in[6 + (l - 1) * 10 + 8];
        const float* prev_b  = (l == 0) ? nullptr : (const float*)d_in[6 + (l - 1) * 10 + 9];

        if (l == 0)
            k_edge<false><<<4096, 256, 0, stream>>>(IN[l], nullptr, nullptr, nullptr,
                                                    rowstart, csr_src, (const _Float16*)attr_h,
                                                    ew, eb, agg16);
        else
            k_edge<true><<<4096, 256, 0, stream>>>(IN[l], prev_s2, prev_g, prev_b,
                                                   rowstart, csr_src, (const _Float16*)attr_h,
                                                   ew, eb, agg16);
        k_mlp1<<<64, 256, 0, stream>>>(agg16, w1t, b1, t16, s1);
        k_mlp2<<<64, 256, 0, stream>>>(t16, w2t, b2, s1, bng, bnb, OUT[l], s2);
    }
    k_bn2<<<(N_NODES * 8 + 255) / 256, 256, 0, stream>>>(bufB, stats + 2 * 512 + 256,
                                                         (const float*)d_in[6 + 2 * 10 + 8],
                                                         (const float*)d_in[6 + 2 * 10 + 9],
                                                         (float*)d_out);
}